// Round 11
// baseline (47.129 us; speedup 1.0000x reference)
//
#include <hip/hip_runtime.h>
#include <stdint.h>

// Problem constants (from reference)
#define N_AG   8
#define S_SAMP 16
#define TB     8192      // T*B
#define DST    128       // D_STATE
#define E_DIM  64

#define CN_STR 9         // cn stride: spreads 16 samples over banks

// WT layout in d_ws (bf16 element offsets): [n][k] row-major, k-stride 128
#define WT1K1  0         // hw1_k1^T  [128][128]
#define WT2K1  16384     // hw2_k1^T  [128][128]
#define WT1K2  32768     // hw1_k2^T  [128][128]
#define WTM3   49152     // rows 0..63 = b1_k^T, rows 64..127 = hb2_k1^T
#define WT2K2  65536     // hw2_k2^T  [64][128]
// f32 regions (float-element offsets from d_ws base)
#define W1WS   36864             // [8192][128]
#define B1WS   (W1WS + 1048576)  // [8192][64]
#define W2WS   (B1WS + 524288)   // [8192][64]
#define B2WS   (W2WS + 524288)   // [8192]
#define WS_FLOATS (B2WS + 8192)  // total floats -> 8568832 bytes

typedef __attribute__((ext_vector_type(8))) short  short8v;   // 8 bf16 = 4 VGPR
typedef __attribute__((ext_vector_type(4))) float  float4v;   // C/D frag

__device__ __forceinline__ float4 ld4(const float* p) { return *(const float4*)p; }

// f32 -> bf16 round-to-nearest-even
__device__ __forceinline__ unsigned short f2bf(float f) {
  uint32_t x = __float_as_uint(f);
  return (unsigned short)((x + 0x7FFFu + ((x >> 16) & 1u)) >> 16);
}
__device__ __forceinline__ uint32_t pk2(float lo, float hi) {
  return (uint32_t)f2bf(lo) | ((uint32_t)f2bf(hi) << 16);
}

// ---------------- JAX threefry2x32 (20 rounds) ----------------
__device__ __forceinline__ uint2 tf2x32(uint32_t k0, uint32_t k1,
                                        uint32_t c0, uint32_t c1) {
  uint32_t ks2 = k0 ^ k1 ^ 0x1BD11BDAu;
  uint32_t x0 = c0 + k0, x1 = c1 + k1;
#define TFR(r) { x0 += x1; x1 = (x1 << (r)) | (x1 >> (32 - (r))); x1 ^= x0; }
  TFR(13) TFR(15) TFR(26) TFR(6)
  x0 += k1;  x1 += ks2 + 1u;
  TFR(17) TFR(29) TFR(16) TFR(24)
  x0 += ks2; x1 += k0 + 2u;
  TFR(13) TFR(15) TFR(26) TFR(6)
  x0 += k0;  x1 += k1 + 3u;
  TFR(17) TFR(29) TFR(16) TFR(24)
  x0 += k1;  x1 += ks2 + 4u;
  TFR(13) TFR(15) TFR(26) TFR(6)
  x0 += ks2; x1 += k0 + 5u;
#undef TFR
  return make_uint2(x0, x1);
}

// Swizzled bf16 LDS tile helpers (R9-verified): rows 256B, byte ^= (row&7)<<4
__device__ __forceinline__ short8v rdfrag(const unsigned short* base, int row, int ks, int lhi) {
  const int b = (row * 256 + ks * 64 + lhi * 16) ^ ((row & 7) << 4);
  return *(const short8v*)((const char*)base + b);
}
__device__ __forceinline__ void wrbf(unsigned short* pan, int r, int c, float v) {
  const int b = (r * 256 + c * 2) ^ ((r & 7) << 4);
  *(unsigned short*)((char*)pan + b) = f2bf(v);
}
// B-fragment directly from global pre-transposed bf16 (R10-verified)
__device__ __forceinline__ short8v gfrag(const unsigned short* wt, int n, int ks, int lhi) {
  return *(const short8v*)(wt + (n << 7) + ks * 32 + lhi * 8);
}

// ========== K0: transpose+convert all weights to bf16 [n][k] in d_ws (R10-verified) ==========
__global__ __launch_bounds__(256)
void wt_transpose(const float* __restrict__ hw1_k1, const float* __restrict__ hw2_k1,
                  const float* __restrict__ hw1_k2, const float* __restrict__ b1_k,
                  const float* __restrict__ hb2_k1, const float* __restrict__ hw2_k2,
                  unsigned short* __restrict__ wt)
{
  __shared__ float t[32][33];
  const int b = blockIdx.x;
  const float* src; int ldn, t0, dstbase;
  if (b < 16)      { src = hw1_k1; ldn = 128; t0 = b;      dstbase = WT1K1; }
  else if (b < 32) { src = hw2_k1; ldn = 128; t0 = b - 16; dstbase = WT2K1; }
  else if (b < 48) { src = hw1_k2; ldn = 128; t0 = b - 32; dstbase = WT1K2; }
  else if (b < 56) { src = b1_k;   ldn = 64;  t0 = b - 48; dstbase = WTM3; }
  else if (b < 64) { src = hb2_k1; ldn = 64;  t0 = b - 56; dstbase = WTM3 + 64 * 128; }
  else             { src = hw2_k2; ldn = 64;  t0 = b - 64; dstbase = WT2K2; }
  const int kt = t0 & 3, nt = t0 >> 2;
  const int tid = threadIdx.x;
  {
    const int c = tid & 31;
    for (int r = tid >> 5; r < 32; r += 8)
      t[r][c] = src[(size_t)(kt * 32 + r) * ldn + nt * 32 + c];
  }
  __syncthreads();
  {
    const int c2 = tid & 15;
    for (int n = tid >> 4; n < 32; n += 16) {
      const uint32_t v = pk2(t[2 * c2][n], t[2 * c2 + 1][n]);
      *(uint32_t*)&wt[dstbase + (nt * 32 + n) * 128 + kt * 32 + 2 * c2] = v;
    }
  }
}

// ========== K1: all hypernet GEMMs (MFMA, RPB=16 -> full M=16), out to d_ws ==========
__global__ __launch_bounds__(256)
void alpha_gemm(const float* __restrict__ states,
                const float* __restrict__ hw1_b1, const float* __restrict__ hw2_b1,
                const float* __restrict__ b1_b,   const float* __restrict__ hb2_b1,
                const float* __restrict__ hw1_b2, const float* __restrict__ hw2_b2,
                const float* __restrict__ hb2_k2, const float* __restrict__ hb2_b2,
                const unsigned short* __restrict__ wt,
                float* __restrict__ w1ws, float* __restrict__ b1ws,
                float* __restrict__ w2ws, float* __restrict__ b2ws)
{
  __shared__ unsigned short xbf[16 * 128];    // X bf16 swz         4 KB
  __shared__ unsigned short h1bf[16 * 128];   // relu(h1) bf16 swz  4 KB
  __shared__ unsigned short h2bf[16 * 128];   // relu(h2) bf16 swz  4 KB
  __shared__ float hbl[16][68];               // hb f32           4.3 KB

  const int tid  = threadIdx.x;
  const int row0 = blockIdx.x * 16;
  const int lane = tid & 63;
  const int wv   = tid >> 6;        // wave 0..3
  const int lrow = lane & 15;       // A-row / B-col within 16-tile
  const int lhi  = lane >> 4;       // k-group; C rows lhi*4+j (all 16 used)

  // ---- stage X (16 rows) as bf16 swz (R9-verified two-pass) ----
#pragma unroll
  for (int pass = 0; pass < 2; ++pass) {
    const int idx = tid + pass * 256;
    const int r = idx >> 5, k0 = (idx & 31) * 4;
    const float4 v = ld4(&states[(size_t)(row0 + r) * DST + k0]);
    const int b = (r * 256 + k0 * 2) ^ ((r & 7) << 4);
    *(uint32_t*)((char*)xbf + b)     = pk2(v.x, v.y);
    *(uint32_t*)((char*)xbf + b + 4) = pk2(v.z, v.w);
  }
  __syncthreads();

  // ===== M1: h1 = relu(X @ hw1_k1 + b) -> h1bf =====
  {
    float4v a0 = {0.f,0.f,0.f,0.f}, a1 = {0.f,0.f,0.f,0.f};
    const int c0 = wv * 32 + lrow, c1 = c0 + 16;
#pragma unroll
    for (int ks = 0; ks < 4; ++ks) {
      const short8v af  = rdfrag(xbf, lrow, ks, lhi);
      a0 = __builtin_amdgcn_mfma_f32_16x16x32_bf16(af, gfrag(wt + WT1K1, c0, ks, lhi), a0, 0, 0, 0);
      a1 = __builtin_amdgcn_mfma_f32_16x16x32_bf16(af, gfrag(wt + WT1K1, c1, ks, lhi), a1, 0, 0, 0);
    }
    const float bv0 = hw1_b1[c0], bv1 = hw1_b1[c1];
#pragma unroll
    for (int j = 0; j < 4; ++j) {
      const int r = lhi * 4 + j;
      wrbf(h1bf, r, c0, fmaxf(a0[j] + bv0, 0.f));
      wrbf(h1bf, r, c1, fmaxf(a1[j] + bv1, 0.f));
    }
  }

  // ===== M2: h2 = relu(X @ hw2_k1 + b) -> h2bf =====
  {
    float4v a0 = {0.f,0.f,0.f,0.f}, a1 = {0.f,0.f,0.f,0.f};
    const int c0 = wv * 32 + lrow, c1 = c0 + 16;
#pragma unroll
    for (int ks = 0; ks < 4; ++ks) {
      const short8v af  = rdfrag(xbf, lrow, ks, lhi);
      a0 = __builtin_amdgcn_mfma_f32_16x16x32_bf16(af, gfrag(wt + WT2K1, c0, ks, lhi), a0, 0, 0, 0);
      a1 = __builtin_amdgcn_mfma_f32_16x16x32_bf16(af, gfrag(wt + WT2K1, c1, ks, lhi), a1, 0, 0, 0);
    }
    const float bv0 = hw2_b1[c0], bv1 = hw2_b1[c1];
#pragma unroll
    for (int j = 0; j < 4; ++j) {
      const int r = lhi * 4 + j;
      wrbf(h2bf, r, c0, fmaxf(a0[j] + bv0, 0.f));
      wrbf(h2bf, r, c1, fmaxf(a1[j] + bv1, 0.f));
    }
  }

  // ===== M3: cols 0..63 -> b1 (global); 64..127 -> hb = relu (LDS) =====
  {
    float4v a0 = {0.f,0.f,0.f,0.f}, a1 = {0.f,0.f,0.f,0.f};
    const int c0 = wv * 32 + lrow, c1 = c0 + 16;
#pragma unroll
    for (int ks = 0; ks < 4; ++ks) {
      const short8v af  = rdfrag(xbf, lrow, ks, lhi);
      a0 = __builtin_amdgcn_mfma_f32_16x16x32_bf16(af, gfrag(wt + WTM3, c0, ks, lhi), a0, 0, 0, 0);
      a1 = __builtin_amdgcn_mfma_f32_16x16x32_bf16(af, gfrag(wt + WTM3, c1, ks, lhi), a1, 0, 0, 0);
    }
#pragma unroll
    for (int j = 0; j < 4; ++j) {
      const int r = lhi * 4 + j;
      if (c0 < 64) b1ws[(size_t)(row0 + r) * 64 + c0] = a0[j] + b1_b[c0];
      else         hbl[r][c0 - 64] = fmaxf(a0[j] + hb2_b1[c0 - 64], 0.f);
      if (c1 < 64) b1ws[(size_t)(row0 + r) * 64 + c1] = a1[j] + b1_b[c1];
      else         hbl[r][c1 - 64] = fmaxf(a1[j] + hb2_b1[c1 - 64], 0.f);
    }
  }
  __syncthreads();   // h1bf/h2bf/hbl now visible to all waves

  // ---- b2[r] = hb . hb2_k2 + b (all 16 rows; 16-lane partial + shuffle) ----
  {
    const int r = tid >> 4, sl = tid & 15;
    float v = hbl[r][sl]      * hb2_k2[sl]
            + hbl[r][sl + 16] * hb2_k2[sl + 16]
            + hbl[r][sl + 32] * hb2_k2[sl + 32]
            + hbl[r][sl + 48] * hb2_k2[sl + 48];
    v += __shfl_down(v, 8, 16); v += __shfl_down(v, 4, 16);
    v += __shfl_down(v, 2, 16); v += __shfl_down(v, 1, 16);
    if (sl == 0) b2ws[row0 + r] = v + hb2_b2[0];
  }

  // ===== M4: w1 = |h1 @ hw1_k2 + b| -> global =====
  {
    float4v a0 = {0.f,0.f,0.f,0.f}, a1 = {0.f,0.f,0.f,0.f};
    const int c0 = wv * 32 + lrow, c1 = c0 + 16;
#pragma unroll
    for (int ks = 0; ks < 4; ++ks) {
      const short8v af  = rdfrag(h1bf, lrow, ks, lhi);
      a0 = __builtin_amdgcn_mfma_f32_16x16x32_bf16(af, gfrag(wt + WT1K2, c0, ks, lhi), a0, 0, 0, 0);
      a1 = __builtin_amdgcn_mfma_f32_16x16x32_bf16(af, gfrag(wt + WT1K2, c1, ks, lhi), a1, 0, 0, 0);
    }
    const float bv0 = hw1_b2[c0], bv1 = hw1_b2[c1];
#pragma unroll
    for (int j = 0; j < 4; ++j) {
      const int r = lhi * 4 + j;
      w1ws[(size_t)(row0 + r) * 128 + c0] = fabsf(a0[j] + bv0);
      w1ws[(size_t)(row0 + r) * 128 + c1] = fabsf(a1[j] + bv1);
    }
  }

  // ===== M5: w2 = |h2 @ hw2_k2 + b| (4 col-tiles, 1 per wave) -> global =====
  {
    float4v a0 = {0.f,0.f,0.f,0.f};
    const int c = wv * 16 + lrow;
#pragma unroll
    for (int ks = 0; ks < 4; ++ks) {
      const short8v af = rdfrag(h2bf, lrow, ks, lhi);
      a0 = __builtin_amdgcn_mfma_f32_16x16x32_bf16(af, gfrag(wt + WT2K2, c, ks, lhi), a0, 0, 0, 0);
    }
    const float bv = hw2_b2[c];
#pragma unroll
    for (int j = 0; j < 4; ++j)
      w2ws[(size_t)(row0 + lhi * 4 + j) * 64 + c] = fabsf(a0[j] + bv);
  }
}

// ========== K2: RNG + ELU main loop + reduce (high occupancy) ==========
__global__ __launch_bounds__(256, 8)
void alpha_main2(const float* __restrict__ q_vals,
                 const float* __restrict__ w1ws, const float* __restrict__ b1ws,
                 const float* __restrict__ w2ws, const float* __restrict__ b2ws,
                 float* __restrict__ out)
{
  __shared__ float w1l[4][132];
  __shared__ float b1l[4][68];
  __shared__ float w2l[4][68];
  __shared__ float b2l[4];
  __shared__ float ql[4][N_AG];
  __shared__ float cn_l[4][S_SAMP][CN_STR];   // cn then |y|

  const int tid  = threadIdx.x;
  const int row0 = blockIdx.x * 4;

  // ---- stage w1/b1/w2 (disjoint thread ranges), b2 + q ----
  if (tid < 128) {
    const int r = tid >> 5, c = (tid & 31) * 4;
    *(float4*)&w1l[r][c] = ld4(&w1ws[(size_t)(row0 + r) * 128 + c]);
  } else if (tid < 192) {
    const int t = tid - 128, r = t >> 4, c = (t & 15) * 4;
    *(float4*)&b1l[r][c] = ld4(&b1ws[(size_t)(row0 + r) * 64 + c]);
  } else {
    const int t = tid - 192, r = t >> 4, c = (t & 15) * 4;
    *(float4*)&w2l[r][c] = ld4(&w2ws[(size_t)(row0 + r) * 64 + c]);
  }
  if (tid < 4) b2l[tid] = b2ws[row0 + tid];
  if (tid < 32) {
    const int rr = tid & 3, a = tid >> 2;
    ql[rr][a] = q_vals[a * TB + row0 + rr];
  }
  __syncthreads();

  // ---- RNG: (row, sample) per thread, tid<64 (verified chain) ----
  if (tid < 64) {
    const int r  = tid >> 4;
    const int sl = tid & 15;
    const uint32_t j = (uint32_t)(row0 + r) * (uint32_t)S_SAMP + (uint32_t)sl;
    uint2 kj  = tf2x32(0u, 42u, 0u, j);       // partitionable split of key(42)
    uint2 sub = tf2x32(kj.x, kj.y, 0u, 1u);   // subkey = split(key_j)[1]
    uint32_t K[N_AG];
#pragma unroll
    for (int i = 0; i < N_AG; ++i) {
      uint2 b = tf2x32(sub.x, sub.y, 0u, (uint32_t)i);
      K[i] = b.x ^ b.y;
    }
    int posa[N_AG];
#pragma unroll
    for (int i = 0; i < N_AG; ++i) {
      int rank = 0;
#pragma unroll
      for (int m = 0; m < N_AG; ++m)
        rank += (K[m] < K[i]) || (K[m] == K[i] && m < i);
      posa[rank] = i;
    }
#pragma unroll
    for (int a = 0; a < N_AG; ++a) {
      const int pa = posa[a];
      float cs = 0.f;
#pragma unroll
      for (int a2 = 0; a2 < N_AG; ++a2)
        cs += (posa[a2] < pa) ? ql[r][a2] : 0.f;
      cn_l[r][sl][a] = cs / (float)max(pa, 1);
    }
  }
  __syncthreads();

  // ---- Main: thread = (r in 4, sl in 16, agent-pair in 4) ----
  {
    const int sl  = tid & 15;
    const int r   = (tid >> 4) & 3;
    const int a0i = (tid >> 6) * 2;   // agents a0i, a0i+1
    const float cn0 = cn_l[r][sl][a0i],     cn1 = cn_l[r][sl][a0i + 1];
    const float qv0 = ql[r][a0i],           qv1 = ql[r][a0i + 1];
    float y0 = 0.f, y1 = 0.f;
#pragma unroll 4
    for (int e = 0; e < E_DIM; e += 4) {
      const float4 wa  = ld4(&w1l[r][e]);
      const float4 wb  = ld4(&w1l[r][64 + e]);
      const float4 bb  = ld4(&b1l[r][e]);
      const float4 w2v = ld4(&w2l[r][e]);
      float h;
      h = fmaf(cn0, wa.x, fmaf(qv0, wb.x, bb.x));
      y0 = fmaf((h > 0.f) ? h : (__expf(h) - 1.f), w2v.x, y0);
      h = fmaf(cn1, wa.x, fmaf(qv1, wb.x, bb.x));
      y1 = fmaf((h > 0.f) ? h : (__expf(h) - 1.f), w2v.x, y1);
      h = fmaf(cn0, wa.y, fmaf(qv0, wb.y, bb.y));
      y0 = fmaf((h > 0.f) ? h : (__expf(h) - 1.f), w2v.y, y0);
      h = fmaf(cn1, wa.y, fmaf(qv1, wb.y, bb.y));
      y1 = fmaf((h > 0.f) ? h : (__expf(h) - 1.f), w2v.y, y1);
      h = fmaf(cn0, wa.z, fmaf(qv0, wb.z, bb.z));
      y0 = fmaf((h > 0.f) ? h : (__expf(h) - 1.f), w2v.z, y0);
      h = fmaf(cn1, wa.z, fmaf(qv1, wb.z, bb.z));
      y1 = fmaf((h > 0.f) ? h : (__expf(h) - 1.f), w2v.z, y1);
      h = fmaf(cn0, wa.w, fmaf(qv0, wb.w, bb.w));
      y0 = fmaf((h > 0.f) ? h : (__expf(h) - 1.f), w2v.w, y0);
      h = fmaf(cn1, wa.w, fmaf(qv1, wb.w, bb.w));
      y1 = fmaf((h > 0.f) ? h : (__expf(h) - 1.f), w2v.w, y1);
    }
    const float b2v = b2l[r];
    cn_l[r][sl][a0i]     = fabsf(y0 + b2v);
    cn_l[r][sl][a0i + 1] = fabsf(y1 + b2v);
  }
  __syncthreads();

  // ---- Reduce over samples ----
  if (tid < 32) {
    const int rr = tid & 3, a = tid >> 2;
    float acc = 0.f;
#pragma unroll
    for (int ss = 0; ss < S_SAMP; ++ss) acc += cn_l[rr][ss][a];
    out[a * TB + row0 + rr] = acc * (1.0f / (float)S_SAMP);
  }
}

// ============ Fallback (R4-structure, proven): used only if ws too small ============
#define FB_RPB 16
#define FB_H_PAD 132
#define FB_E_PAD 68
__global__ __launch_bounds__(256)
void alpha_fused2(const float* __restrict__ q_vals, const float* __restrict__ states,
                  const float* __restrict__ hw1_k1, const float* __restrict__ hw1_b1,
                  const float* __restrict__ hw1_k2, const float* __restrict__ hw1_b2,
                  const float* __restrict__ b1_k,   const float* __restrict__ b1_b,
                  const float* __restrict__ hw2_k1, const float* __restrict__ hw2_b1,
                  const float* __restrict__ hw2_k2, const float* __restrict__ hw2_b2,
                  const float* __restrict__ hb2_k1, const float* __restrict__ hb2_b1,
                  const float* __restrict__ hb2_k2, const float* __restrict__ hb2_b2,
                  float* __restrict__ out)
{
  __shared__ float s_lds[FB_RPB][DST];
  __shared__ float scratch[FB_RPB][FB_H_PAD];
  __shared__ float scratch2[FB_RPB][FB_E_PAD];
  __shared__ float w1l[FB_RPB][FB_H_PAD];
  __shared__ float b1l[FB_RPB][FB_E_PAD];
  __shared__ float w2l[FB_RPB][FB_E_PAD];
  __shared__ float b2l[FB_RPB];
  __shared__ float qlf[FB_RPB][N_AG];
  __shared__ float cnred[FB_RPB][S_SAMP][N_AG];
  const int tid = threadIdx.x;
  const int row0 = blockIdx.x * FB_RPB;
  const int r = tid >> 4, sl = tid & 15;
  {
    const float4* src = reinterpret_cast<const float4*>(states + (size_t)row0 * DST);
    reinterpret_cast<float4*>(&s_lds[0][0])[tid]       = src[tid];
    reinterpret_cast<float4*>(&s_lds[0][0])[tid + 256] = src[tid + 256];
  }
  if (tid < FB_RPB * N_AG) {
    const int rr = tid >> 3, a = tid & 7;
    qlf[rr][a] = q_vals[a * TB + row0 + rr];
  }
  __syncthreads();
  {
    const uint32_t j = (uint32_t)(row0 + r) * (uint32_t)S_SAMP + (uint32_t)sl;
    uint2 kj = tf2x32(0u, 42u, 0u, j);
    uint2 sub = tf2x32(kj.x, kj.y, 0u, 1u);
    uint32_t K[N_AG];
#pragma unroll
    for (int i = 0; i < N_AG; ++i) { uint2 b = tf2x32(sub.x, sub.y, 0u, (uint32_t)i); K[i] = b.x ^ b.y; }
    int posa[N_AG];
#pragma unroll
    for (int i = 0; i < N_AG; ++i) {
      int rank = 0;
#pragma unroll
      for (int m = 0; m < N_AG; ++m) rank += (K[m] < K[i]) || (K[m] == K[i] && m < i);
      posa[rank] = i;
    }
#pragma unroll
    for (int a = 0; a < N_AG; ++a) {
      const int pa = posa[a];
      float cs = 0.f;
#pragma unroll
      for (int a2 = 0; a2 < N_AG; ++a2) cs += (posa[a2] < pa) ? qlf[r][a2] : 0.f;
      cnred[r][sl][a] = cs / (float)max(pa, 1);
    }
  }
  {
    int c = tid & 127, rg = tid >> 7;
    float a0=0.f,a1=0.f,a2=0.f,a3=0.f,a4=0.f,a5=0.f,a6=0.f,a7=0.f;
#pragma unroll 2
    for (int k = 0; k < DST; ++k) {
      float wv = hw1_k1[k * 128 + c];
      a0 += s_lds[rg*8+0][k]*wv; a1 += s_lds[rg*8+1][k]*wv;
      a2 += s_lds[rg*8+2][k]*wv; a3 += s_lds[rg*8+3][k]*wv;
      a4 += s_lds[rg*8+4][k]*wv; a5 += s_lds[rg*8+5][k]*wv;
      a6 += s_lds[rg*8+6][k]*wv; a7 += s_lds[rg*8+7][k]*wv;
    }
    float b = hw1_b1[c];
    scratch[rg*8+0][c]=fmaxf(a0+b,0.f); scratch[rg*8+1][c]=fmaxf(a1+b,0.f);
    scratch[rg*8+2][c]=fmaxf(a2+b,0.f); scratch[rg*8+3][c]=fmaxf(a3+b,0.f);
    scratch[rg*8+4][c]=fmaxf(a4+b,0.f); scratch[rg*8+5][c]=fmaxf(a5+b,0.f);
    scratch[rg*8+6][c]=fmaxf(a6+b,0.f); scratch[rg*8+7][c]=fmaxf(a7+b,0.f);
  }
  {
    int c = tid & 63, rg = tid >> 6;
    float a0=0.f,a1=0.f,a2=0.f,a3=0.f;
#pragma unroll 2
    for (int k = 0; k < DST; ++k) {
      float wv = b1_k[k * 64 + c];
      a0 += s_lds[rg*4+0][k]*wv; a1 += s_lds[rg*4+1][k]*wv;
      a2 += s_lds[rg*4+2][k]*wv; a3 += s_lds[rg*4+3][k]*wv;
    }
    float b = b1_b[c];
    b1l[rg*4+0][c]=a0+b; b1l[rg*4+1][c]=a1+b; b1l[rg*4+2][c]=a2+b; b1l[rg*4+3][c]=a3+b;
  }
  __syncthreads();
  {
    int c = tid & 127, rg = tid >> 7;
    float a0=0.f,a1=0.f,a2=0.f,a3=0.f,a4=0.f,a5=0.f,a6=0.f,a7=0.f;
#pragma unroll 2
    for (int k = 0; k < DST; ++k) {
      float wv = hw1_k2[k * 128 + c];
      a0 += scratch[rg*8+0][k]*wv; a1 += scratch[rg*8+1][k]*wv;
      a2 += scratch[rg*8+2][k]*wv; a3 += scratch[rg*8+3][k]*wv;
      a4 += scratch[rg*8+4][k]*wv; a5 += scratch[rg*8+5][k]*wv;
      a6 += scratch[rg*8+6][k]*wv; a7 += scratch[rg*8+7][k]*wv;
    }
    float b = hw1_b2[c];
    w1l[rg*8+0][c]=fabsf(a0+b); w1l[rg*8+1][c]=fabsf(a1+b);
    w1l[rg*8+2][c]=fabsf(a2+b); w1l[rg*8+3][c]=fabsf(a3+b);
    w1l[rg*8+4][c]=fabsf(a4+b); w1l[rg*8+5][c]=fabsf(a5+b);
    w1l[rg*8+6][c]=fabsf(a6+b); w1l[rg*8+7][c]=fabsf(a7+b);
  }
  {
    int c = tid & 63, rg = tid >> 6;
    float a0=0.f,a1=0.f,a2=0.f,a3=0.f;
#pragma unroll 2
    for (int k = 0; k < DST; ++k) {
      float wv = hb2_k1[k * 64 + c];
      a0 += s_lds[rg*4+0][k]*wv; a1 += s_lds[rg*4+1][k]*wv;
      a2 += s_lds[rg*4+2][k]*wv; a3 += s_lds[rg*4+3][k]*wv;
    }
    float b = hb2_b1[c];
    scratch2[rg*4+0][c]=fmaxf(a0+b,0.f); scratch2[rg*4+1][c]=fmaxf(a1+b,0.f);
    scratch2[rg*4+2][c]=fmaxf(a2+b,0.f); scratch2[rg*4+3][c]=fmaxf(a3+b,0.f);
  }
  __syncthreads();
  {
    int c = tid & 127, rg = tid >> 7;
    float a0=0.f,a1=0.f,a2=0.f,a3=0.f,a4=0.f,a5=0.f,a6=0.f,a7=0.f;
#pragma unroll 2
    for (int k = 0; k < DST; ++k) {
      float wv = hw2_k1[k * 128 + c];
      a0 += s_lds[rg*8+0][k]*wv; a1 += s_lds[rg*8+1][k]*wv;
      a2 += s_lds[rg*8+2][k]*wv; a3 += s_lds[rg*8+3][k]*wv;
      a4 += s_lds[rg*8+4][k]*wv; a5 += s_lds[rg*8+5][k]*wv;
      a6 += s_lds[rg*8+6][k]*wv; a7 += s_lds[rg*8+7][k]*wv;
    }
    float b = hw2_b1[c];
    scratch[rg*8+0][c]=fmaxf(a0+b,0.f); scratch[rg*8+1][c]=fmaxf(a1+b,0.f);
    scratch[rg*8+2][c]=fmaxf(a2+b,0.f); scratch[rg*8+3][c]=fmaxf(a3+b,0.f);
    scratch[rg*8+4][c]=fmaxf(a4+b,0.f); scratch[rg*8+5][c]=fmaxf(a5+b,0.f);
    scratch[rg*8+6][c]=fmaxf(a6+b,0.f); scratch[rg*8+7][c]=fmaxf(a7+b,0.f);
  }
  if (tid < FB_RPB * S_SAMP) {
    float v = scratch2[r][sl]      * hb2_k2[sl]
            + scratch2[r][sl + 16] * hb2_k2[sl + 16]
            + scratch2[r][sl + 32] * hb2_k2[sl + 32]
            + scratch2[r][sl + 48] * hb2_k2[sl + 48];
    v += __shfl_down(v, 8, 16); v += __shfl_down(v, 4, 16);
    v += __shfl_down(v, 2, 16); v += __shfl_down(v, 1, 16);
    if (sl == 0) b2l[r] = v + hb2_b2[0];
  }
  __syncthreads();
  {
    int c = tid & 63, rg = tid >> 6;
    float a0=0.f,a1=0.f,a2=0.f,a3=0.f;
#pragma unroll 2
    for (int k = 0; k < DST; ++k) {
      float wv = hw2_k2[k * 64 + c];
      a0 += scratch[rg*4+0][k]*wv; a1 += scratch[rg*4+1][k]*wv;
      a2 += scratch[rg*4+2][k]*wv; a3 += scratch[rg*4+3][k]*wv;
    }
    float b = hw2_b2[c];
    w2l[rg*4+0][c]=fabsf(a0+b); w2l[rg*4+1][c]=fabsf(a1+b);
    w2l[rg*4+2][c]=fabsf(a2+b); w2l[rg*4+3][c]=fabsf(a3+b);
  }
  __syncthreads();
  {
    float cn[N_AG], qv[N_AG], y[N_AG];
#pragma unroll
    for (int a = 0; a < N_AG; ++a) { cn[a]=cnred[r][sl][a]; qv[a]=qlf[r][a]; y[a]=0.f; }
#pragma unroll 4
    for (int e = 0; e < E_DIM; e += 4) {
      const float4 wa  = ld4(&w1l[r][e]);
      const float4 wb  = ld4(&w1l[r][64 + e]);
      const float4 bb  = ld4(&b1l[r][e]);
      const float4 w2v = ld4(&w2l[r][e]);
#pragma unroll
      for (int a = 0; a < N_AG; ++a) {
        float h;
        h = fmaf(cn[a], wa.x, fmaf(qv[a], wb.x, bb.x));
        y[a] = fmaf((h > 0.f) ? h : (__expf(h) - 1.f), w2v.x, y[a]);
        h = fmaf(cn[a], wa.y, fmaf(qv[a], wb.y, bb.y));
        y[a] = fmaf((h > 0.f) ? h : (__expf(h) - 1.f), w2v.y, y[a]);
        h = fmaf(cn[a], wa.z, fmaf(qv[a], wb.z, bb.z));
        y[a] = fmaf((h > 0.f) ? h : (__expf(h) - 1.f), w2v.z, y[a]);
        h = fmaf(cn[a], wa.w, fmaf(qv[a], wb.w, bb.w));
        y[a] = fmaf((h > 0.f) ? h : (__expf(h) - 1.f), w2v.w, y[a]);
      }
    }
    const float b2v = b2l[r];
#pragma unroll
    for (int a = 0; a < N_AG; ++a) cnred[r][sl][a] = fabsf(y[a] + b2v);
  }
  __syncthreads();
  if (tid < FB_RPB * N_AG) {
    const int a = tid >> 4, rr = tid & 15;
    float acc = 0.f;
#pragma unroll
    for (int ss = 0; ss < S_SAMP; ++ss) acc += cnred[rr][ss][a];
    out[a * TB + row0 + rr] = acc * (1.0f / (float)S_SAMP);
  }
}

extern "C" void kernel_launch(void* const* d_in, const int* in_sizes, int n_in,
                              void* d_out, int out_size, void* d_ws, size_t ws_size,
                              hipStream_t stream) {
  const float* q_vals = (const float*)d_in[0];
  const float* states = (const float*)d_in[1];
  const float* hw1_k1 = (const float*)d_in[2];
  const float* hw1_b1 = (const float*)d_in[3];
  const float* hw1_k2 = (const float*)d_in[4];
  const float* hw1_b2 = (const float*)d_in[5];
  const float* b1_k   = (const float*)d_in[6];
  const float* b1_b   = (const float*)d_in[7];
  const float* hw2_k1 = (const float*)d_in[8];
  const float* hw2_b1 = (const float*)d_in[9];
  const float* hw2_k2 = (const float*)d_in[10];
  const float* hw2_b2 = (const float*)d_in[11];
  const float* hb2_k1 = (const float*)d_in[12];
  const float* hb2_b1 = (const float*)d_in[13];
  const float* hb2_k2 = (const float*)d_in[14];
  const float* hb2_b2 = (const float*)d_in[15];
  float* out = (float*)d_out;

  const size_t need = (size_t)WS_FLOATS * sizeof(float);
  if (ws_size >= need) {
    unsigned short* wt = (unsigned short*)d_ws;
    float* wsf  = (float*)d_ws;
    float* w1ws = wsf + W1WS;
    float* b1ws = wsf + B1WS;
    float* w2ws = wsf + W2WS;
    float* b2ws = wsf + B2WS;
    wt_transpose<<<dim3(72), 256, 0, stream>>>(
        hw1_k1, hw2_k1, hw1_k2, b1_k, hb2_k1, hw2_k2, wt);
    alpha_gemm<<<dim3(TB / 16), 256, 0, stream>>>(
        states, hw1_b1, hw2_b1, b1_b, hb2_b1, hw1_b2, hw2_b2,
        hb2_k2, hb2_b2, wt, w1ws, b1ws, w2ws, b2ws);
    alpha_main2<<<dim3(TB / 4), 256, 0, stream>>>(
        q_vals, w1ws, b1ws, w2ws, b2ws, out);
  } else {
    alpha_fused2<<<dim3(TB / FB_RPB), 256, 0, stream>>>(
        q_vals, states, hw1_k1, hw1_b1, hw1_k2, hw1_b2, b1_k, b1_b,
        hw2_k1, hw2_b1, hw2_k2, hw2_b2, hb2_k1, hb2_b1, hb2_k2, hb2_b2, out);
  }
}

// Round 12
// 41.871 us; speedup vs baseline: 1.1256x; 1.1256x over previous
//
#include <hip/hip_runtime.h>
#include <stdint.h>

// Problem constants (from reference)
#define N_AG   8
#define S_SAMP 16
#define TB     8192      // T*B
#define DST    128       // D_STATE
#define E_DIM  64

#define RPB    8         // rows per block -> 1024 blocks = 4 blocks/CU
#define CN_STR 9         // cn stride: spreads 16 samples over banks

// WT layout in d_ws (bf16 element offsets): [n][k] row-major, k-stride 128
#define WT1K1  0         // hw1_k1^T  [128][128]
#define WT2K1  16384     // hw2_k1^T  [128][128]
#define WT1K2  32768     // hw1_k2^T  [128][128]
#define WTM3   49152     // rows 0..63 = b1_k^T, rows 64..127 = hb2_k1^T
#define WT2K2  65536     // hw2_k2^T  [64][128]
#define WT_ELEMS 73728   // total bf16 elements (147456 B)

typedef __attribute__((ext_vector_type(8))) short  short8v;   // 8 bf16 = 4 VGPR
typedef __attribute__((ext_vector_type(4))) float  float4v;   // C/D frag

__device__ __forceinline__ float4 ld4(const float* p) { return *(const float4*)p; }

// f32 -> bf16 round-to-nearest-even
__device__ __forceinline__ unsigned short f2bf(float f) {
  uint32_t x = __float_as_uint(f);
  return (unsigned short)((x + 0x7FFFu + ((x >> 16) & 1u)) >> 16);
}
__device__ __forceinline__ uint32_t pk2(float lo, float hi) {
  return (uint32_t)f2bf(lo) | ((uint32_t)f2bf(hi) << 16);
}

// ---------------- JAX threefry2x32 (20 rounds) ----------------
__device__ __forceinline__ uint2 tf2x32(uint32_t k0, uint32_t k1,
                                        uint32_t c0, uint32_t c1) {
  uint32_t ks2 = k0 ^ k1 ^ 0x1BD11BDAu;
  uint32_t x0 = c0 + k0, x1 = c1 + k1;
#define TFR(r) { x0 += x1; x1 = (x1 << (r)) | (x1 >> (32 - (r))); x1 ^= x0; }
  TFR(13) TFR(15) TFR(26) TFR(6)
  x0 += k1;  x1 += ks2 + 1u;
  TFR(17) TFR(29) TFR(16) TFR(24)
  x0 += ks2; x1 += k0 + 2u;
  TFR(13) TFR(15) TFR(26) TFR(6)
  x0 += k0;  x1 += k1 + 3u;
  TFR(17) TFR(29) TFR(16) TFR(24)
  x0 += k1;  x1 += ks2 + 4u;
  TFR(13) TFR(15) TFR(26) TFR(6)
  x0 += ks2; x1 += k0 + 5u;
#undef TFR
  return make_uint2(x0, x1);
}

// Swizzled bf16 LDS tile helpers (R9-verified): rows 256B, byte ^= (row&7)<<4
__device__ __forceinline__ short8v rdfrag(const unsigned short* base, int row, int ks, int lhi) {
  const int b = (row * 256 + ks * 64 + lhi * 16) ^ ((row & 7) << 4);
  return *(const short8v*)((const char*)base + b);
}
__device__ __forceinline__ void wrbf(unsigned short* pan, int r, int c, float v) {
  const int b = (r * 256 + c * 2) ^ ((r & 7) << 4);
  *(unsigned short*)((char*)pan + b) = f2bf(v);
}
// B-fragment directly from global pre-transposed bf16 (R10-verified)
__device__ __forceinline__ short8v gfrag(const unsigned short* wt, int n, int ks, int lhi) {
  return *(const short8v*)(wt + (n << 7) + ks * 32 + lhi * 8);
}

// ========== K0: transpose+convert all weights to bf16 [n][k] in d_ws (R10-verified) ==========
__global__ __launch_bounds__(256)
void wt_transpose(const float* __restrict__ hw1_k1, const float* __restrict__ hw2_k1,
                  const float* __restrict__ hw1_k2, const float* __restrict__ b1_k,
                  const float* __restrict__ hb2_k1, const float* __restrict__ hw2_k2,
                  unsigned short* __restrict__ wt)
{
  __shared__ float t[32][33];
  const int b = blockIdx.x;
  const float* src; int ldn, t0, dstbase;
  if (b < 16)      { src = hw1_k1; ldn = 128; t0 = b;      dstbase = WT1K1; }
  else if (b < 32) { src = hw2_k1; ldn = 128; t0 = b - 16; dstbase = WT2K1; }
  else if (b < 48) { src = hw1_k2; ldn = 128; t0 = b - 32; dstbase = WT1K2; }
  else if (b < 56) { src = b1_k;   ldn = 64;  t0 = b - 48; dstbase = WTM3; }
  else if (b < 64) { src = hb2_k1; ldn = 64;  t0 = b - 56; dstbase = WTM3 + 64 * 128; }
  else             { src = hw2_k2; ldn = 64;  t0 = b - 64; dstbase = WT2K2; }
  const int kt = t0 & 3, nt = t0 >> 2;
  const int tid = threadIdx.x;
  {
    const int c = tid & 31;
    for (int r = tid >> 5; r < 32; r += 8)
      t[r][c] = src[(size_t)(kt * 32 + r) * ldn + nt * 32 + c];
  }
  __syncthreads();
  {
    const int c2 = tid & 15;
    for (int n = tid >> 4; n < 32; n += 16) {
      const uint32_t v = pk2(t[2 * c2][n], t[2 * c2 + 1][n]);
      *(uint32_t*)&wt[dstbase + (nt * 32 + n) * 128 + kt * 32 + 2 * c2] = v;
    }
  }
}

// ========================= Main fused kernel (R10-verified structure) =========================
// R12 change: __launch_bounds__(256, 4) caps VGPR at 128 so all 4 blocks/CU
// are co-resident (R9 measured 140 VGPR -> 3/CU + exposed straggler round).
__global__ __launch_bounds__(256, 4)
void alpha_mfma2(const float* __restrict__ q_vals,   // (8, 8192)
                 const float* __restrict__ states,   // (8192, 128)
                 const float* __restrict__ hw1_b1, const float* __restrict__ hw1_b2,
                 const float* __restrict__ b1_b,   const float* __restrict__ hw2_b1,
                 const float* __restrict__ hw2_b2, const float* __restrict__ hb2_b1,
                 const float* __restrict__ hb2_k2, const float* __restrict__ hb2_b2,
                 const unsigned short* __restrict__ wt,
                 float* __restrict__ out)            // (8, 8192)
{
  __shared__ unsigned short xbf[RPB * 128];     // X bf16 swz            2 KB
  __shared__ unsigned short h1bf[RPB * 128];    // relu(h1) bf16 swz     2 KB
  __shared__ unsigned short h2bf[RPB * 128];    // relu(h2) bf16 swz     2 KB
  __shared__ float w1l[RPB][132];               // |w1| f32            4.2 KB
  __shared__ float b1l[RPB][68];                //                     2.2 KB
  __shared__ float w2l[RPB][68];                //                     2.2 KB
  __shared__ float hbl[RPB][68];                //                     2.2 KB
  __shared__ float b2l[RPB];
  __shared__ float ql[RPB][N_AG];
  __shared__ float cn_l[RPB][S_SAMP][CN_STR];   // cn then |y|         4.6 KB

  const int tid  = threadIdx.x;
  const int row0 = blockIdx.x * RPB;
  const int lane = tid & 63;
  const int wv   = tid >> 6;        // wave 0..3
  const int lrow = lane & 15;       // A-row / B-col within a 16-tile
  const int lhi  = lane >> 4;       // k-group; C rows lhi*4+j (valid if lhi<2)

  // ---- P0: X f32 -> bf16 swz LDS (8 rows); q load ----
  {
    const int r = tid >> 5, k0 = (tid & 31) * 4;
    const float4 v = ld4(&states[(size_t)(row0 + r) * DST + k0]);
    const int b = (r * 256 + k0 * 2) ^ ((r & 7) << 4);
    *(uint32_t*)((char*)xbf + b)     = pk2(v.x, v.y);
    *(uint32_t*)((char*)xbf + b + 4) = pk2(v.z, v.w);
  }
  if (tid < RPB * N_AG) {
    const int rr = tid >> 3, a = tid & 7;
    ql[rr][a] = q_vals[a * TB + row0 + rr];
  }
  __syncthreads();

  // ---- RNG: one (row, sample) per thread (verified chain) ----
  if (tid < RPB * S_SAMP) {
    const int r  = tid >> 4;
    const int sl = tid & 15;
    const uint32_t j = (uint32_t)(row0 + r) * (uint32_t)S_SAMP + (uint32_t)sl;
    uint2 kj  = tf2x32(0u, 42u, 0u, j);       // partitionable split of key(42)
    uint2 sub = tf2x32(kj.x, kj.y, 0u, 1u);   // subkey = split(key_j)[1]
    uint32_t K[N_AG];
#pragma unroll
    for (int i = 0; i < N_AG; ++i) {
      uint2 b = tf2x32(sub.x, sub.y, 0u, (uint32_t)i);
      K[i] = b.x ^ b.y;
    }
    int posa[N_AG];
#pragma unroll
    for (int i = 0; i < N_AG; ++i) {
      int rank = 0;
#pragma unroll
      for (int m = 0; m < N_AG; ++m)
        rank += (K[m] < K[i]) || (K[m] == K[i] && m < i);
      posa[rank] = i;
    }
#pragma unroll
    for (int a = 0; a < N_AG; ++a) {
      const int pa = posa[a];
      float cs = 0.f;
#pragma unroll
      for (int a2 = 0; a2 < N_AG; ++a2)
        cs += (posa[a2] < pa) ? ql[r][a2] : 0.f;
      cn_l[r][sl][a] = cs / (float)max(pa, 1);
    }
  }

  // ===== M1: h1 = relu(X @ hw1_k1 + b) -> h1bf =====
  {
    float4v a0 = {0.f,0.f,0.f,0.f}, a1 = {0.f,0.f,0.f,0.f};
    const int c0 = wv * 32 + lrow, c1 = c0 + 16;
#pragma unroll
    for (int ks = 0; ks < 4; ++ks) {
      const short8v af  = rdfrag(xbf, lrow & 7, ks, lhi);
      const short8v b0  = gfrag(wt + WT1K1, c0, ks, lhi);
      const short8v b1f = gfrag(wt + WT1K1, c1, ks, lhi);
      a0 = __builtin_amdgcn_mfma_f32_16x16x32_bf16(af, b0,  a0, 0, 0, 0);
      a1 = __builtin_amdgcn_mfma_f32_16x16x32_bf16(af, b1f, a1, 0, 0, 0);
    }
    if (lhi < 2) {
      const float bv0 = hw1_b1[c0], bv1 = hw1_b1[c1];
#pragma unroll
      for (int j = 0; j < 4; ++j) {
        const int r = lhi * 4 + j;
        wrbf(h1bf, r, c0, fmaxf(a0[j] + bv0, 0.f));
        wrbf(h1bf, r, c1, fmaxf(a1[j] + bv1, 0.f));
      }
    }
  }

  // ===== M2: h2 = relu(X @ hw2_k1 + b) -> h2bf =====
  {
    float4v a0 = {0.f,0.f,0.f,0.f}, a1 = {0.f,0.f,0.f,0.f};
    const int c0 = wv * 32 + lrow, c1 = c0 + 16;
#pragma unroll
    for (int ks = 0; ks < 4; ++ks) {
      const short8v af  = rdfrag(xbf, lrow & 7, ks, lhi);
      const short8v b0  = gfrag(wt + WT2K1, c0, ks, lhi);
      const short8v b1f = gfrag(wt + WT2K1, c1, ks, lhi);
      a0 = __builtin_amdgcn_mfma_f32_16x16x32_bf16(af, b0,  a0, 0, 0, 0);
      a1 = __builtin_amdgcn_mfma_f32_16x16x32_bf16(af, b1f, a1, 0, 0, 0);
    }
    if (lhi < 2) {
      const float bv0 = hw2_b1[c0], bv1 = hw2_b1[c1];
#pragma unroll
      for (int j = 0; j < 4; ++j) {
        const int r = lhi * 4 + j;
        wrbf(h2bf, r, c0, fmaxf(a0[j] + bv0, 0.f));
        wrbf(h2bf, r, c1, fmaxf(a1[j] + bv1, 0.f));
      }
    }
  }

  // ===== M3: cols 0..63 -> b1 = X@b1_k + b; 64..127 -> hb = relu(X@hb2_k1 + b) =====
  {
    float4v a0 = {0.f,0.f,0.f,0.f}, a1 = {0.f,0.f,0.f,0.f};
    const int c0 = wv * 32 + lrow, c1 = c0 + 16;
#pragma unroll
    for (int ks = 0; ks < 4; ++ks) {
      const short8v af  = rdfrag(xbf, lrow & 7, ks, lhi);
      const short8v b0  = gfrag(wt + WTM3, c0, ks, lhi);
      const short8v b1f = gfrag(wt + WTM3, c1, ks, lhi);
      a0 = __builtin_amdgcn_mfma_f32_16x16x32_bf16(af, b0,  a0, 0, 0, 0);
      a1 = __builtin_amdgcn_mfma_f32_16x16x32_bf16(af, b1f, a1, 0, 0, 0);
    }
    if (lhi < 2) {
#pragma unroll
      for (int j = 0; j < 4; ++j) {
        const int r = lhi * 4 + j;
        if (c0 < 64) b1l[r][c0] = a0[j] + b1_b[c0];
        else         hbl[r][c0 - 64] = fmaxf(a0[j] + hb2_b1[c0 - 64], 0.f);
        if (c1 < 64) b1l[r][c1] = a1[j] + b1_b[c1];
        else         hbl[r][c1 - 64] = fmaxf(a1[j] + hb2_b1[c1 - 64], 0.f);
      }
    }
  }
  __syncthreads();   // h1bf/h2bf/b1l/hbl now visible

  // ---- b2[r] = hb . hb2_k2 + b (16-lane partial + shuffle) ----
  if (tid < RPB * S_SAMP) {
    const int r = tid >> 4, sl = tid & 15;
    float v = hbl[r][sl]      * hb2_k2[sl]
            + hbl[r][sl + 16] * hb2_k2[sl + 16]
            + hbl[r][sl + 32] * hb2_k2[sl + 32]
            + hbl[r][sl + 48] * hb2_k2[sl + 48];
    v += __shfl_down(v, 8, 16); v += __shfl_down(v, 4, 16);
    v += __shfl_down(v, 2, 16); v += __shfl_down(v, 1, 16);
    if (sl == 0) b2l[r] = v + hb2_b2[0];
  }

  // ===== M4: w1 = |h1 @ hw1_k2 + b| -> w1l (f32) =====
  {
    float4v a0 = {0.f,0.f,0.f,0.f}, a1 = {0.f,0.f,0.f,0.f};
    const int c0 = wv * 32 + lrow, c1 = c0 + 16;
#pragma unroll
    for (int ks = 0; ks < 4; ++ks) {
      const short8v af  = rdfrag(h1bf, lrow & 7, ks, lhi);
      const short8v b0  = gfrag(wt + WT1K2, c0, ks, lhi);
      const short8v b1f = gfrag(wt + WT1K2, c1, ks, lhi);
      a0 = __builtin_amdgcn_mfma_f32_16x16x32_bf16(af, b0,  a0, 0, 0, 0);
      a1 = __builtin_amdgcn_mfma_f32_16x16x32_bf16(af, b1f, a1, 0, 0, 0);
    }
    if (lhi < 2) {
      const float bv0 = hw1_b2[c0], bv1 = hw1_b2[c1];
#pragma unroll
      for (int j = 0; j < 4; ++j) {
        const int r = lhi * 4 + j;
        w1l[r][c0] = fabsf(a0[j] + bv0);
        w1l[r][c1] = fabsf(a1[j] + bv1);
      }
    }
  }

  // ===== M5: w2 = |h2 @ hw2_k2 + b| (4 col-tiles, 1 per wave) =====
  {
    float4v a0 = {0.f,0.f,0.f,0.f};
    const int c = wv * 16 + lrow;
#pragma unroll
    for (int ks = 0; ks < 4; ++ks) {
      const short8v af = rdfrag(h2bf, lrow & 7, ks, lhi);
      const short8v b0 = gfrag(wt + WT2K2, c, ks, lhi);
      a0 = __builtin_amdgcn_mfma_f32_16x16x32_bf16(af, b0, a0, 0, 0, 0);
    }
    if (lhi < 2) {
      const float bv = hw2_b2[c];
#pragma unroll
      for (int j = 0; j < 4; ++j)
        w2l[lhi * 4 + j][c] = fabsf(a0[j] + bv);
    }
  }
  __syncthreads();   // w1l/w2l/b2l visible

  // ===== Main: thread = (r, sl, agent-half), all 256 active (R4-verified) =====
  {
    const int sl = tid & 15;
    const int r  = (tid >> 4) & 7;
    const int a0i = (tid >> 7) * 4;   // agents a0i..a0i+3
    float cn[4], qv[4], y[4];
#pragma unroll
    for (int jj = 0; jj < 4; ++jj) {
      cn[jj] = cn_l[r][sl][a0i + jj];
      qv[jj] = ql[r][a0i + jj];
      y[jj]  = 0.f;
    }
#pragma unroll 4
    for (int e = 0; e < E_DIM; e += 4) {
      const float4 wa  = ld4(&w1l[r][e]);
      const float4 wb  = ld4(&w1l[r][64 + e]);
      const float4 bb  = ld4(&b1l[r][e]);
      const float4 w2v = ld4(&w2l[r][e]);
#pragma unroll
      for (int jj = 0; jj < 4; ++jj) {
        float h;
        h = fmaf(cn[jj], wa.x, fmaf(qv[jj], wb.x, bb.x));
        y[jj] = fmaf((h > 0.f) ? h : (__expf(h) - 1.f), w2v.x, y[jj]);
        h = fmaf(cn[jj], wa.y, fmaf(qv[jj], wb.y, bb.y));
        y[jj] = fmaf((h > 0.f) ? h : (__expf(h) - 1.f), w2v.y, y[jj]);
        h = fmaf(cn[jj], wa.z, fmaf(qv[jj], wb.z, bb.z));
        y[jj] = fmaf((h > 0.f) ? h : (__expf(h) - 1.f), w2v.z, y[jj]);
        h = fmaf(cn[jj], wa.w, fmaf(qv[jj], wb.w, bb.w));
        y[jj] = fmaf((h > 0.f) ? h : (__expf(h) - 1.f), w2v.w, y[jj]);
      }
    }
    const float b2v = b2l[r];
#pragma unroll
    for (int jj = 0; jj < 4; ++jj)
      cn_l[r][sl][a0i + jj] = fabsf(y[jj] + b2v);
  }
  __syncthreads();

  // ---- Reduce over samples; rr = tid&7 so 8 consecutive rows coalesce ----
  if (tid < RPB * N_AG) {
    const int rr = tid & 7, a = tid >> 3;
    float acc = 0.f;
#pragma unroll
    for (int ss = 0; ss < S_SAMP; ++ss) acc += cn_l[rr][ss][a];
    out[a * TB + row0 + rr] = acc * (1.0f / (float)S_SAMP);
  }
}

// ============ Fallback (R4-structure, proven): used only if ws too small ============
#define FB_RPB 16
#define FB_H_PAD 132
#define FB_E_PAD 68
__global__ __launch_bounds__(256)
void alpha_fused2(const float* __restrict__ q_vals, const float* __restrict__ states,
                  const float* __restrict__ hw1_k1, const float* __restrict__ hw1_b1,
                  const float* __restrict__ hw1_k2, const float* __restrict__ hw1_b2,
                  const float* __restrict__ b1_k,   const float* __restrict__ b1_b,
                  const float* __restrict__ hw2_k1, const float* __restrict__ hw2_b1,
                  const float* __restrict__ hw2_k2, const float* __restrict__ hw2_b2,
                  const float* __restrict__ hb2_k1, const float* __restrict__ hb2_b1,
                  const float* __restrict__ hb2_k2, const float* __restrict__ hb2_b2,
                  float* __restrict__ out)
{
  __shared__ float s_lds[FB_RPB][DST];
  __shared__ float scratch[FB_RPB][FB_H_PAD];
  __shared__ float scratch2[FB_RPB][FB_E_PAD];
  __shared__ float w1l[FB_RPB][FB_H_PAD];
  __shared__ float b1l[FB_RPB][FB_E_PAD];
  __shared__ float w2l[FB_RPB][FB_E_PAD];
  __shared__ float b2l[FB_RPB];
  __shared__ float qlf[FB_RPB][N_AG];
  __shared__ float cnred[FB_RPB][S_SAMP][N_AG];
  const int tid = threadIdx.x;
  const int row0 = blockIdx.x * FB_RPB;
  const int r = tid >> 4, sl = tid & 15;
  {
    const float4* src = reinterpret_cast<const float4*>(states + (size_t)row0 * DST);
    reinterpret_cast<float4*>(&s_lds[0][0])[tid]       = src[tid];
    reinterpret_cast<float4*>(&s_lds[0][0])[tid + 256] = src[tid + 256];
  }
  if (tid < FB_RPB * N_AG) {
    const int rr = tid >> 3, a = tid & 7;
    qlf[rr][a] = q_vals[a * TB + row0 + rr];
  }
  __syncthreads();
  {
    const uint32_t j = (uint32_t)(row0 + r) * (uint32_t)S_SAMP + (uint32_t)sl;
    uint2 kj = tf2x32(0u, 42u, 0u, j);
    uint2 sub = tf2x32(kj.x, kj.y, 0u, 1u);
    uint32_t K[N_AG];
#pragma unroll
    for (int i = 0; i < N_AG; ++i) { uint2 b = tf2x32(sub.x, sub.y, 0u, (uint32_t)i); K[i] = b.x ^ b.y; }
    int posa[N_AG];
#pragma unroll
    for (int i = 0; i < N_AG; ++i) {
      int rank = 0;
#pragma unroll
      for (int m = 0; m < N_AG; ++m) rank += (K[m] < K[i]) || (K[m] == K[i] && m < i);
      posa[rank] = i;
    }
#pragma unroll
    for (int a = 0; a < N_AG; ++a) {
      const int pa = posa[a];
      float cs = 0.f;
#pragma unroll
      for (int a2 = 0; a2 < N_AG; ++a2) cs += (posa[a2] < pa) ? qlf[r][a2] : 0.f;
      cnred[r][sl][a] = cs / (float)max(pa, 1);
    }
  }
  {
    int c = tid & 127, rg = tid >> 7;
    float a0=0.f,a1=0.f,a2=0.f,a3=0.f,a4=0.f,a5=0.f,a6=0.f,a7=0.f;
#pragma unroll 2
    for (int k = 0; k < DST; ++k) {
      float wv = hw1_k1[k * 128 + c];
      a0 += s_lds[rg*8+0][k]*wv; a1 += s_lds[rg*8+1][k]*wv;
      a2 += s_lds[rg*8+2][k]*wv; a3 += s_lds[rg*8+3][k]*wv;
      a4 += s_lds[rg*8+4][k]*wv; a5 += s_lds[rg*8+5][k]*wv;
      a6 += s_lds[rg*8+6][k]*wv; a7 += s_lds[rg*8+7][k]*wv;
    }
    float b = hw1_b1[c];
    scratch[rg*8+0][c]=fmaxf(a0+b,0.f); scratch[rg*8+1][c]=fmaxf(a1+b,0.f);
    scratch[rg*8+2][c]=fmaxf(a2+b,0.f); scratch[rg*8+3][c]=fmaxf(a3+b,0.f);
    scratch[rg*8+4][c]=fmaxf(a4+b,0.f); scratch[rg*8+5][c]=fmaxf(a5+b,0.f);
    scratch[rg*8+6][c]=fmaxf(a6+b,0.f); scratch[rg*8+7][c]=fmaxf(a7+b,0.f);
  }
  {
    int c = tid & 63, rg = tid >> 6;
    float a0=0.f,a1=0.f,a2=0.f,a3=0.f;
#pragma unroll 2
    for (int k = 0; k < DST; ++k) {
      float wv = b1_k[k * 64 + c];
      a0 += s_lds[rg*4+0][k]*wv; a1 += s_lds[rg*4+1][k]*wv;
      a2 += s_lds[rg*4+2][k]*wv; a3 += s_lds[rg*4+3][k]*wv;
    }
    float b = b1_b[c];
    b1l[rg*4+0][c]=a0+b; b1l[rg*4+1][c]=a1+b; b1l[rg*4+2][c]=a2+b; b1l[rg*4+3][c]=a3+b;
  }
  __syncthreads();
  {
    int c = tid & 127, rg = tid >> 7;
    float a0=0.f,a1=0.f,a2=0.f,a3=0.f,a4=0.f,a5=0.f,a6=0.f,a7=0.f;
#pragma unroll 2
    for (int k = 0; k < DST; ++k) {
      float wv = hw1_k2[k * 128 + c];
      a0 += scratch[rg*8+0][k]*wv; a1 += scratch[rg*8+1][k]*wv;
      a2 += scratch[rg*8+2][k]*wv; a3 += scratch[rg*8+3][k]*wv;
      a4 += scratch[rg*8+4][k]*wv; a5 += scratch[rg*8+5][k]*wv;
      a6 += scratch[rg*8+6][k]*wv; a7 += scratch[rg*8+7][k]*wv;
    }
    float b = hw1_b2[c];
    w1l[rg*8+0][c]=fabsf(a0+b); w1l[rg*8+1][c]=fabsf(a1+b);
    w1l[rg*8+2][c]=fabsf(a2+b); w1l[rg*8+3][c]=fabsf(a3+b);
    w1l[rg*8+4][c]=fabsf(a4+b); w1l[rg*8+5][c]=fabsf(a5+b);
    w1l[rg*8+6][c]=fabsf(a6+b); w1l[rg*8+7][c]=fabsf(a7+b);
  }
  {
    int c = tid & 63, rg = tid >> 6;
    float a0=0.f,a1=0.f,a2=0.f,a3=0.f;
#pragma unroll 2
    for (int k = 0; k < DST; ++k) {
      float wv = hb2_k1[k * 64 + c];
      a0 += s_lds[rg*4+0][k]*wv; a1 += s_lds[rg*4+1][k]*wv;
      a2 += s_lds[rg*4+2][k]*wv; a3 += s_lds[rg*4+3][k]*wv;
    }
    float b = hb2_b1[c];
    scratch2[rg*4+0][c]=fmaxf(a0+b,0.f); scratch2[rg*4+1][c]=fmaxf(a1+b,0.f);
    scratch2[rg*4+2][c]=fmaxf(a2+b,0.f); scratch2[rg*4+3][c]=fmaxf(a3+b,0.f);
  }
  __syncthreads();
  {
    int c = tid & 127, rg = tid >> 7;
    float a0=0.f,a1=0.f,a2=0.f,a3=0.f,a4=0.f,a5=0.f,a6=0.f,a7=0.f;
#pragma unroll 2
    for (int k = 0; k < DST; ++k) {
      float wv = hw2_k1[k * 128 + c];
      a0 += s_lds[rg*8+0][k]*wv; a1 += s_lds[rg*8+1][k]*wv;
      a2 += s_lds[rg*8+2][k]*wv; a3 += s_lds[rg*8+3][k]*wv;
      a4 += s_lds[rg*8+4][k]*wv; a5 += s_lds[rg*8+5][k]*wv;
      a6 += s_lds[rg*8+6][k]*wv; a7 += s_lds[rg*8+7][k]*wv;
    }
    float b = hw2_b1[c];
    scratch[rg*8+0][c]=fmaxf(a0+b,0.f); scratch[rg*8+1][c]=fmaxf(a1+b,0.f);
    scratch[rg*8+2][c]=fmaxf(a2+b,0.f); scratch[rg*8+3][c]=fmaxf(a3+b,0.f);
    scratch[rg*8+4][c]=fmaxf(a4+b,0.f); scratch[rg*8+5][c]=fmaxf(a5+b,0.f);
    scratch[rg*8+6][c]=fmaxf(a6+b,0.f); scratch[rg*8+7][c]=fmaxf(a7+b,0.f);
  }
  if (tid < FB_RPB * S_SAMP) {
    float v = scratch2[r][sl]      * hb2_k2[sl]
            + scratch2[r][sl + 16] * hb2_k2[sl + 16]
            + scratch2[r][sl + 32] * hb2_k2[sl + 32]
            + scratch2[r][sl + 48] * hb2_k2[sl + 48];
    v += __shfl_down(v, 8, 16); v += __shfl_down(v, 4, 16);
    v += __shfl_down(v, 2, 16); v += __shfl_down(v, 1, 16);
    if (sl == 0) b2l[r] = v + hb2_b2[0];
  }
  __syncthreads();
  {
    int c = tid & 63, rg = tid >> 6;
    float a0=0.f,a1=0.f,a2=0.f,a3=0.f;
#pragma unroll 2
    for (int k = 0; k < DST; ++k) {
      float wv = hw2_k2[k * 64 + c];
      a0 += scratch[rg*4+0][k]*wv; a1 += scratch[rg*4+1][k]*wv;
      a2 += scratch[rg*4+2][k]*wv; a3 += scratch[rg*4+3][k]*wv;
    }
    float b = hw2_b2[c];
    w2l[rg*4+0][c]=fabsf(a0+b); w2l[rg*4+1][c]=fabsf(a1+b);
    w2l[rg*4+2][c]=fabsf(a2+b); w2l[rg*4+3][c]=fabsf(a3+b);
  }
  __syncthreads();
  {
    float cn[N_AG], qv[N_AG], y[N_AG];
#pragma unroll
    for (int a = 0; a < N_AG; ++a) { cn[a]=cnred[r][sl][a]; qv[a]=qlf[r][a]; y[a]=0.f; }
#pragma unroll 4
    for (int e = 0; e < E_DIM; e += 4) {
      const float4 wa  = ld4(&w1l[r][e]);
      const float4 wb  = ld4(&w1l[r][64 + e]);
      const float4 bb  = ld4(&b1l[r][e]);
      const float4 w2v = ld4(&w2l[r][e]);
#pragma unroll
      for (int a = 0; a < N_AG; ++a) {
        float h;
        h = fmaf(cn[a], wa.x, fmaf(qv[a], wb.x, bb.x));
        y[a] = fmaf((h > 0.f) ? h : (__expf(h) - 1.f), w2v.x, y[a]);
        h = fmaf(cn[a], wa.y, fmaf(qv[a], wb.y, bb.y));
        y[a] = fmaf((h > 0.f) ? h : (__expf(h) - 1.f), w2v.y, y[a]);
        h = fmaf(cn[a], wa.z, fmaf(qv[a], wb.z, bb.z));
        y[a] = fmaf((h > 0.f) ? h : (__expf(h) - 1.f), w2v.z, y[a]);
        h = fmaf(cn[a], wa.w, fmaf(qv[a], wb.w, bb.w));
        y[a] = fmaf((h > 0.f) ? h : (__expf(h) - 1.f), w2v.w, y[a]);
      }
    }
    const float b2v = b2l[r];
#pragma unroll
    for (int a = 0; a < N_AG; ++a) cnred[r][sl][a] = fabsf(y[a] + b2v);
  }
  __syncthreads();
  if (tid < FB_RPB * N_AG) {
    const int a = tid >> 4, rr = tid & 15;
    float acc = 0.f;
#pragma unroll
    for (int ss = 0; ss < S_SAMP; ++ss) acc += cnred[rr][ss][a];
    out[a * TB + row0 + rr] = acc * (1.0f / (float)S_SAMP);
  }
}

extern "C" void kernel_launch(void* const* d_in, const int* in_sizes, int n_in,
                              void* d_out, int out_size, void* d_ws, size_t ws_size,
                              hipStream_t stream) {
  const float* q_vals = (const float*)d_in[0];
  const float* states = (const float*)d_in[1];
  const float* hw1_k1 = (const float*)d_in[2];
  const float* hw1_b1 = (const float*)d_in[3];
  const float* hw1_k2 = (const float*)d_in[4];
  const float* hw1_b2 = (const float*)d_in[5];
  const float* b1_k   = (const float*)d_in[6];
  const float* b1_b   = (const float*)d_in[7];
  const float* hw2_k1 = (const float*)d_in[8];
  const float* hw2_b1 = (const float*)d_in[9];
  const float* hw2_k2 = (const float*)d_in[10];
  const float* hw2_b2 = (const float*)d_in[11];
  const float* hb2_k1 = (const float*)d_in[12];
  const float* hb2_b1 = (const float*)d_in[13];
  const float* hb2_k2 = (const float*)d_in[14];
  const float* hb2_b2 = (const float*)d_in[15];
  float* out = (float*)d_out;

  const size_t need = (size_t)WT_ELEMS * sizeof(unsigned short);
  if (ws_size >= need) {
    unsigned short* wt = (unsigned short*)d_ws;
    wt_transpose<<<dim3(72), 256, 0, stream>>>(
        hw1_k1, hw2_k1, hw1_k2, b1_k, hb2_k1, hw2_k2, wt);
    alpha_mfma2<<<dim3(TB / RPB), 256, 0, stream>>>(
        q_vals, states, hw1_b1, hw1_b2, b1_b, hw2_b1, hw2_b2, hb2_b1,
        hb2_k2, hb2_b2, wt, out);
  } else {
    alpha_fused2<<<dim3(TB / FB_RPB), 256, 0, stream>>>(
        q_vals, states, hw1_k1, hw1_b1, hw1_k2, hw1_b2, b1_k, b1_b,
        hw2_k1, hw2_b1, hw2_k2, hw2_b2, hb2_k1, hb2_b1, hb2_k2, hb2_b2, out);
  }
}

// Round 14
// 41.401 us; speedup vs baseline: 1.1383x; 1.0114x over previous
//
#include <hip/hip_runtime.h>
#include <stdint.h>

// Problem constants (from reference)
#define N_AG   8
#define S_SAMP 16
#define TB     8192      // T*B
#define DST    128       // D_STATE
#define E_DIM  64

#define RPB    8         // rows per block -> 1024 blocks = 4 blocks/CU
#define CN_STR 9         // cn stride: spreads 16 samples over banks

// WT layout in d_ws (bf16 element offsets): [n][k] row-major, k-stride 128
#define WT1K1  0         // hw1_k1^T  [128][128]
#define WT2K1  16384     // hw2_k1^T  [128][128]
#define WT1K2  32768     // hw1_k2^T  [128][128]
#define WTM3   49152     // rows 0..63 = b1_k^T, rows 64..127 = hb2_k1^T
#define WT2K2  65536     // hw2_k2^T  [64][128]
#define WT_ELEMS 73728   // total bf16 elements (147456 B)

typedef __attribute__((ext_vector_type(8))) short  short8v;   // 8 bf16 = 4 VGPR
typedef __attribute__((ext_vector_type(4))) float  float4v;   // C/D frag

__device__ __forceinline__ float4 ld4(const float* p) { return *(const float4*)p; }

// f32 -> bf16 round-to-nearest-even
__device__ __forceinline__ unsigned short f2bf(float f) {
  uint32_t x = __float_as_uint(f);
  return (unsigned short)((x + 0x7FFFu + ((x >> 16) & 1u)) >> 16);
}
__device__ __forceinline__ uint32_t pk2(float lo, float hi) {
  return (uint32_t)f2bf(lo) | ((uint32_t)f2bf(hi) << 16);
}

// ---------------- JAX threefry2x32 (20 rounds) ----------------
__device__ __forceinline__ uint2 tf2x32(uint32_t k0, uint32_t k1,
                                        uint32_t c0, uint32_t c1) {
  uint32_t ks2 = k0 ^ k1 ^ 0x1BD11BDAu;
  uint32_t x0 = c0 + k0, x1 = c1 + k1;
#define TFR(r) { x0 += x1; x1 = (x1 << (r)) | (x1 >> (32 - (r))); x1 ^= x0; }
  TFR(13) TFR(15) TFR(26) TFR(6)
  x0 += k1;  x1 += ks2 + 1u;
  TFR(17) TFR(29) TFR(16) TFR(24)
  x0 += ks2; x1 += k0 + 2u;
  TFR(13) TFR(15) TFR(26) TFR(6)
  x0 += k0;  x1 += k1 + 3u;
  TFR(17) TFR(29) TFR(16) TFR(24)
  x0 += k1;  x1 += ks2 + 4u;
  TFR(13) TFR(15) TFR(26) TFR(6)
  x0 += ks2; x1 += k0 + 5u;
#undef TFR
  return make_uint2(x0, x1);
}

// Swizzled bf16 LDS tile helpers (R9-verified): rows 256B, byte ^= (row&7)<<4
__device__ __forceinline__ short8v rdfrag(const unsigned short* base, int row, int ks, int lhi) {
  const int b = (row * 256 + ks * 64 + lhi * 16) ^ ((row & 7) << 4);
  return *(const short8v*)((const char*)base + b);
}
__device__ __forceinline__ void wrbf(unsigned short* pan, int r, int c, float v) {
  const int b = (r * 256 + c * 2) ^ ((r & 7) << 4);
  *(unsigned short*)((char*)pan + b) = f2bf(v);
}
// B-fragment directly from global pre-transposed bf16 (R10-verified)
__device__ __forceinline__ short8v gfrag(const unsigned short* wt, int n, int ks, int lhi) {
  return *(const short8v*)(wt + (n << 7) + ks * 32 + lhi * 8);
}

// ========== K0: transpose+convert all weights to bf16 [n][k] in d_ws (R10-verified) ==========
__global__ __launch_bounds__(256)
void wt_transpose(const float* __restrict__ hw1_k1, const float* __restrict__ hw2_k1,
                  const float* __restrict__ hw1_k2, const float* __restrict__ b1_k,
                  const float* __restrict__ hb2_k1, const float* __restrict__ hw2_k2,
                  unsigned short* __restrict__ wt)
{
  __shared__ float t[32][33];
  const int b = blockIdx.x;
  const float* src; int ldn, t0, dstbase;
  if (b < 16)      { src = hw1_k1; ldn = 128; t0 = b;      dstbase = WT1K1; }
  else if (b < 32) { src = hw2_k1; ldn = 128; t0 = b - 16; dstbase = WT2K1; }
  else if (b < 48) { src = hw1_k2; ldn = 128; t0 = b - 32; dstbase = WT1K2; }
  else if (b < 56) { src = b1_k;   ldn = 64;  t0 = b - 48; dstbase = WTM3; }
  else if (b < 64) { src = hb2_k1; ldn = 64;  t0 = b - 56; dstbase = WTM3 + 64 * 128; }
  else             { src = hw2_k2; ldn = 64;  t0 = b - 64; dstbase = WT2K2; }
  const int kt = t0 & 3, nt = t0 >> 2;
  const int tid = threadIdx.x;
  {
    const int c = tid & 31;
    for (int r = tid >> 5; r < 32; r += 8)
      t[r][c] = src[(size_t)(kt * 32 + r) * ldn + nt * 32 + c];
  }
  __syncthreads();
  {
    const int c2 = tid & 15;
    for (int n = tid >> 4; n < 32; n += 16) {
      const uint32_t v = pk2(t[2 * c2][n], t[2 * c2 + 1][n]);
      *(uint32_t*)&wt[dstbase + (nt * 32 + n) * 128 + kt * 32 + 2 * c2] = v;
    }
  }
}

// ========================= Main fused kernel (R10-verified structure) =========================
// R12/R14: __launch_bounds__(256, 4) caps VGPR at 128 so all 4 blocks/CU
// are co-resident. R14 = exact revert to the R12 build (R13's balanced-RNG
// variant showed post-timing nondeterminism and is withdrawn).
__global__ __launch_bounds__(256, 4)
void alpha_mfma2(const float* __restrict__ q_vals,   // (8, 8192)
                 const float* __restrict__ states,   // (8192, 128)
                 const float* __restrict__ hw1_b1, const float* __restrict__ hw1_b2,
                 const float* __restrict__ b1_b,   const float* __restrict__ hw2_b1,
                 const float* __restrict__ hw2_b2, const float* __restrict__ hb2_b1,
                 const float* __restrict__ hb2_k2, const float* __restrict__ hb2_b2,
                 const unsigned short* __restrict__ wt,
                 float* __restrict__ out)            // (8, 8192)
{
  __shared__ unsigned short xbf[RPB * 128];     // X bf16 swz            2 KB
  __shared__ unsigned short h1bf[RPB * 128];    // relu(h1) bf16 swz     2 KB
  __shared__ unsigned short h2bf[RPB * 128];    // relu(h2) bf16 swz     2 KB
  __shared__ float w1l[RPB][132];               // |w1| f32            4.2 KB
  __shared__ float b1l[RPB][68];                //                     2.2 KB
  __shared__ float w2l[RPB][68];                //                     2.2 KB
  __shared__ float hbl[RPB][68];                //                     2.2 KB
  __shared__ float b2l[RPB];
  __shared__ float ql[RPB][N_AG];
  __shared__ float cn_l[RPB][S_SAMP][CN_STR];   // cn then |y|         4.6 KB

  const int tid  = threadIdx.x;
  const int row0 = blockIdx.x * RPB;
  const int lane = tid & 63;
  const int wv   = tid >> 6;        // wave 0..3
  const int lrow = lane & 15;       // A-row / B-col within a 16-tile
  const int lhi  = lane >> 4;       // k-group; C rows lhi*4+j (valid if lhi<2)

  // ---- P0: X f32 -> bf16 swz LDS (8 rows); q load ----
  {
    const int r = tid >> 5, k0 = (tid & 31) * 4;
    const float4 v = ld4(&states[(size_t)(row0 + r) * DST + k0]);
    const int b = (r * 256 + k0 * 2) ^ ((r & 7) << 4);
    *(uint32_t*)((char*)xbf + b)     = pk2(v.x, v.y);
    *(uint32_t*)((char*)xbf + b + 4) = pk2(v.z, v.w);
  }
  if (tid < RPB * N_AG) {
    const int rr = tid >> 3, a = tid & 7;
    ql[rr][a] = q_vals[a * TB + row0 + rr];
  }
  __syncthreads();

  // ---- RNG: one (row, sample) per thread (verified chain) ----
  if (tid < RPB * S_SAMP) {
    const int r  = tid >> 4;
    const int sl = tid & 15;
    const uint32_t j = (uint32_t)(row0 + r) * (uint32_t)S_SAMP + (uint32_t)sl;
    uint2 kj  = tf2x32(0u, 42u, 0u, j);       // partitionable split of key(42)
    uint2 sub = tf2x32(kj.x, kj.y, 0u, 1u);   // subkey = split(key_j)[1]
    uint32_t K[N_AG];
#pragma unroll
    for (int i = 0; i < N_AG; ++i) {
      uint2 b = tf2x32(sub.x, sub.y, 0u, (uint32_t)i);
      K[i] = b.x ^ b.y;
    }
    int posa[N_AG];
#pragma unroll
    for (int i = 0; i < N_AG; ++i) {
      int rank = 0;
#pragma unroll
      for (int m = 0; m < N_AG; ++m)
        rank += (K[m] < K[i]) || (K[m] == K[i] && m < i);
      posa[rank] = i;
    }
#pragma unroll
    for (int a = 0; a < N_AG; ++a) {
      const int pa = posa[a];
      float cs = 0.f;
#pragma unroll
      for (int a2 = 0; a2 < N_AG; ++a2)
        cs += (posa[a2] < pa) ? ql[r][a2] : 0.f;
      cn_l[r][sl][a] = cs / (float)max(pa, 1);
    }
  }

  // ===== M1: h1 = relu(X @ hw1_k1 + b) -> h1bf =====
  {
    float4v a0 = {0.f,0.f,0.f,0.f}, a1 = {0.f,0.f,0.f,0.f};
    const int c0 = wv * 32 + lrow, c1 = c0 + 16;
#pragma unroll
    for (int ks = 0; ks < 4; ++ks) {
      const short8v af  = rdfrag(xbf, lrow & 7, ks, lhi);
      const short8v b0  = gfrag(wt + WT1K1, c0, ks, lhi);
      const short8v b1f = gfrag(wt + WT1K1, c1, ks, lhi);
      a0 = __builtin_amdgcn_mfma_f32_16x16x32_bf16(af, b0,  a0, 0, 0, 0);
      a1 = __builtin_amdgcn_mfma_f32_16x16x32_bf16(af, b1f, a1, 0, 0, 0);
    }
    if (lhi < 2) {
      const float bv0 = hw1_b1[c0], bv1 = hw1_b1[c1];
#pragma unroll
      for (int j = 0; j < 4; ++j) {
        const int r = lhi * 4 + j;
        wrbf(h1bf, r, c0, fmaxf(a0[j] + bv0, 0.f));
        wrbf(h1bf, r, c1, fmaxf(a1[j] + bv1, 0.f));
      }
    }
  }

  // ===== M2: h2 = relu(X @ hw2_k1 + b) -> h2bf =====
  {
    float4v a0 = {0.f,0.f,0.f,0.f}, a1 = {0.f,0.f,0.f,0.f};
    const int c0 = wv * 32 + lrow, c1 = c0 + 16;
#pragma unroll
    for (int ks = 0; ks < 4; ++ks) {
      const short8v af  = rdfrag(xbf, lrow & 7, ks, lhi);
      const short8v b0  = gfrag(wt + WT2K1, c0, ks, lhi);
      const short8v b1f = gfrag(wt + WT2K1, c1, ks, lhi);
      a0 = __builtin_amdgcn_mfma_f32_16x16x32_bf16(af, b0,  a0, 0, 0, 0);
      a1 = __builtin_amdgcn_mfma_f32_16x16x32_bf16(af, b1f, a1, 0, 0, 0);
    }
    if (lhi < 2) {
      const float bv0 = hw2_b1[c0], bv1 = hw2_b1[c1];
#pragma unroll
      for (int j = 0; j < 4; ++j) {
        const int r = lhi * 4 + j;
        wrbf(h2bf, r, c0, fmaxf(a0[j] + bv0, 0.f));
        wrbf(h2bf, r, c1, fmaxf(a1[j] + bv1, 0.f));
      }
    }
  }

  // ===== M3: cols 0..63 -> b1 = X@b1_k + b; 64..127 -> hb = relu(X@hb2_k1 + b) =====
  {
    float4v a0 = {0.f,0.f,0.f,0.f}, a1 = {0.f,0.f,0.f,0.f};
    const int c0 = wv * 32 + lrow, c1 = c0 + 16;
#pragma unroll
    for (int ks = 0; ks < 4; ++ks) {
      const short8v af  = rdfrag(xbf, lrow & 7, ks, lhi);
      const short8v b0  = gfrag(wt + WTM3, c0, ks, lhi);
      const short8v b1f = gfrag(wt + WTM3, c1, ks, lhi);
      a0 = __builtin_amdgcn_mfma_f32_16x16x32_bf16(af, b0,  a0, 0, 0, 0);
      a1 = __builtin_amdgcn_mfma_f32_16x16x32_bf16(af, b1f, a1, 0, 0, 0);
    }
    if (lhi < 2) {
#pragma unroll
      for (int j = 0; j < 4; ++j) {
        const int r = lhi * 4 + j;
        if (c0 < 64) b1l[r][c0] = a0[j] + b1_b[c0];
        else         hbl[r][c0 - 64] = fmaxf(a0[j] + hb2_b1[c0 - 64], 0.f);
        if (c1 < 64) b1l[r][c1] = a1[j] + b1_b[c1];
        else         hbl[r][c1 - 64] = fmaxf(a1[j] + hb2_b1[c1 - 64], 0.f);
      }
    }
  }
  __syncthreads();   // h1bf/h2bf/b1l/hbl now visible

  // ---- b2[r] = hb . hb2_k2 + b (16-lane partial + shuffle) ----
  if (tid < RPB * S_SAMP) {
    const int r = tid >> 4, sl = tid & 15;
    float v = hbl[r][sl]      * hb2_k2[sl]
            + hbl[r][sl + 16] * hb2_k2[sl + 16]
            + hbl[r][sl + 32] * hb2_k2[sl + 32]
            + hbl[r][sl + 48] * hb2_k2[sl + 48];
    v += __shfl_down(v, 8, 16); v += __shfl_down(v, 4, 16);
    v += __shfl_down(v, 2, 16); v += __shfl_down(v, 1, 16);
    if (sl == 0) b2l[r] = v + hb2_b2[0];
  }

  // ===== M4: w1 = |h1 @ hw1_k2 + b| -> w1l (f32) =====
  {
    float4v a0 = {0.f,0.f,0.f,0.f}, a1 = {0.f,0.f,0.f,0.f};
    const int c0 = wv * 32 + lrow, c1 = c0 + 16;
#pragma unroll
    for (int ks = 0; ks < 4; ++ks) {
      const short8v af  = rdfrag(h1bf, lrow & 7, ks, lhi);
      const short8v b0  = gfrag(wt + WT1K2, c0, ks, lhi);
      const short8v b1f = gfrag(wt + WT1K2, c1, ks, lhi);
      a0 = __builtin_amdgcn_mfma_f32_16x16x32_bf16(af, b0,  a0, 0, 0, 0);
      a1 = __builtin_amdgcn_mfma_f32_16x16x32_bf16(af, b1f, a1, 0, 0, 0);
    }
    if (lhi < 2) {
      const float bv0 = hw1_b2[c0], bv1 = hw1_b2[c1];
#pragma unroll
      for (int j = 0; j < 4; ++j) {
        const int r = lhi * 4 + j;
        w1l[r][c0] = fabsf(a0[j] + bv0);
        w1l[r][c1] = fabsf(a1[j] + bv1);
      }
    }
  }

  // ===== M5: w2 = |h2 @ hw2_k2 + b| (4 col-tiles, 1 per wave) =====
  {
    float4v a0 = {0.f,0.f,0.f,0.f};
    const int c = wv * 16 + lrow;
#pragma unroll
    for (int ks = 0; ks < 4; ++ks) {
      const short8v af = rdfrag(h2bf, lrow & 7, ks, lhi);
      const short8v b0 = gfrag(wt + WT2K2, c, ks, lhi);
      a0 = __builtin_amdgcn_mfma_f32_16x16x32_bf16(af, b0, a0, 0, 0, 0);
    }
    if (lhi < 2) {
      const float bv = hw2_b2[c];
#pragma unroll
      for (int j = 0; j < 4; ++j)
        w2l[lhi * 4 + j][c] = fabsf(a0[j] + bv);
    }
  }
  __syncthreads();   // w1l/w2l/b2l visible

  // ===== Main: thread = (r, sl, agent-half), all 256 active (R4-verified) =====
  {
    const int sl = tid & 15;
    const int r  = (tid >> 4) & 7;
    const int a0i = (tid >> 7) * 4;   // agents a0i..a0i+3
    float cn[4], qv[4], y[4];
#pragma unroll
    for (int jj = 0; jj < 4; ++jj) {
      cn[jj] = cn_l[r][sl][a0i + jj];
      qv[jj] = ql[r][a0i + jj];
      y[jj]  = 0.f;
    }
#pragma unroll 4
    for (int e = 0; e < E_DIM; e += 4) {
      const float4 wa  = ld4(&w1l[r][e]);
      const float4 wb  = ld4(&w1l[r][64 + e]);
      const float4 bb  = ld4(&b1l[r][e]);
      const float4 w2v = ld4(&w2l[r][e]);
#pragma unroll
      for (int jj = 0; jj < 4; ++jj) {
        float h;
        h = fmaf(cn[jj], wa.x, fmaf(qv[jj], wb.x, bb.x));
        y[jj] = fmaf((h > 0.f) ? h : (__expf(h) - 1.f), w2v.x, y[jj]);
        h = fmaf(cn[jj], wa.y, fmaf(qv[jj], wb.y, bb.y));
        y[jj] = fmaf((h > 0.f) ? h : (__expf(h) - 1.f), w2v.y, y[jj]);
        h = fmaf(cn[jj], wa.z, fmaf(qv[jj], wb.z, bb.z));
        y[jj] = fmaf((h > 0.f) ? h : (__expf(h) - 1.f), w2v.z, y[jj]);
        h = fmaf(cn[jj], wa.w, fmaf(qv[jj], wb.w, bb.w));
        y[jj] = fmaf((h > 0.f) ? h : (__expf(h) - 1.f), w2v.w, y[jj]);
      }
    }
    const float b2v = b2l[r];
#pragma unroll
    for (int jj = 0; jj < 4; ++jj)
      cn_l[r][sl][a0i + jj] = fabsf(y[jj] + b2v);
  }
  __syncthreads();

  // ---- Reduce over samples; rr = tid&7 so 8 consecutive rows coalesce ----
  if (tid < RPB * N_AG) {
    const int rr = tid & 7, a = tid >> 3;
    float acc = 0.f;
#pragma unroll
    for (int ss = 0; ss < S_SAMP; ++ss) acc += cn_l[rr][ss][a];
    out[a * TB + row0 + rr] = acc * (1.0f / (float)S_SAMP);
  }
}

// ============ Fallback (R4-structure, proven): used only if ws too small ============
#define FB_RPB 16
#define FB_H_PAD 132
#define FB_E_PAD 68
__global__ __launch_bounds__(256)
void alpha_fused2(const float* __restrict__ q_vals, const float* __restrict__ states,
                  const float* __restrict__ hw1_k1, const float* __restrict__ hw1_b1,
                  const float* __restrict__ hw1_k2, const float* __restrict__ hw1_b2,
                  const float* __restrict__ b1_k,   const float* __restrict__ b1_b,
                  const float* __restrict__ hw2_k1, const float* __restrict__ hw2_b1,
                  const float* __restrict__ hw2_k2, const float* __restrict__ hw2_b2,
                  const float* __restrict__ hb2_k1, const float* __restrict__ hb2_b1,
                  const float* __restrict__ hb2_k2, const float* __restrict__ hb2_b2,
                  float* __restrict__ out)
{
  __shared__ float s_lds[FB_RPB][DST];
  __shared__ float scratch[FB_RPB][FB_H_PAD];
  __shared__ float scratch2[FB_RPB][FB_E_PAD];
  __shared__ float w1l[FB_RPB][FB_H_PAD];
  __shared__ float b1l[FB_RPB][FB_E_PAD];
  __shared__ float w2l[FB_RPB][FB_E_PAD];
  __shared__ float b2l[FB_RPB];
  __shared__ float qlf[FB_RPB][N_AG];
  __shared__ float cnred[FB_RPB][S_SAMP][N_AG];
  const int tid = threadIdx.x;
  const int row0 = blockIdx.x * FB_RPB;
  const int r = tid >> 4, sl = tid & 15;
  {
    const float4* src = reinterpret_cast<const float4*>(states + (size_t)row0 * DST);
    reinterpret_cast<float4*>(&s_lds[0][0])[tid]       = src[tid];
    reinterpret_cast<float4*>(&s_lds[0][0])[tid + 256] = src[tid + 256];
  }
  if (tid < FB_RPB * N_AG) {
    const int rr = tid >> 3, a = tid & 7;
    qlf[rr][a] = q_vals[a * TB + row0 + rr];
  }
  __syncthreads();
  {
    const uint32_t j = (uint32_t)(row0 + r) * (uint32_t)S_SAMP + (uint32_t)sl;
    uint2 kj = tf2x32(0u, 42u, 0u, j);
    uint2 sub = tf2x32(kj.x, kj.y, 0u, 1u);
    uint32_t K[N_AG];
#pragma unroll
    for (int i = 0; i < N_AG; ++i) { uint2 b = tf2x32(sub.x, sub.y, 0u, (uint32_t)i); K[i] = b.x ^ b.y; }
    int posa[N_AG];
#pragma unroll
    for (int i = 0; i < N_AG; ++i) {
      int rank = 0;
#pragma unroll
      for (int m = 0; m < N_AG; ++m) rank += (K[m] < K[i]) || (K[m] == K[i] && m < i);
      posa[rank] = i;
    }
#pragma unroll
    for (int a = 0; a < N_AG; ++a) {
      const int pa = posa[a];
      float cs = 0.f;
#pragma unroll
      for (int a2 = 0; a2 < N_AG; ++a2) cs += (posa[a2] < pa) ? qlf[r][a2] : 0.f;
      cnred[r][sl][a] = cs / (float)max(pa, 1);
    }
  }
  {
    int c = tid & 127, rg = tid >> 7;
    float a0=0.f,a1=0.f,a2=0.f,a3=0.f,a4=0.f,a5=0.f,a6=0.f,a7=0.f;
#pragma unroll 2
    for (int k = 0; k < DST; ++k) {
      float wv = hw1_k1[k * 128 + c];
      a0 += s_lds[rg*8+0][k]*wv; a1 += s_lds[rg*8+1][k]*wv;
      a2 += s_lds[rg*8+2][k]*wv; a3 += s_lds[rg*8+3][k]*wv;
      a4 += s_lds[rg*8+4][k]*wv; a5 += s_lds[rg*8+5][k]*wv;
      a6 += s_lds[rg*8+6][k]*wv; a7 += s_lds[rg*8+7][k]*wv;
    }
    float b = hw1_b1[c];
    scratch[rg*8+0][c]=fmaxf(a0+b,0.f); scratch[rg*8+1][c]=fmaxf(a1+b,0.f);
    scratch[rg*8+2][c]=fmaxf(a2+b,0.f); scratch[rg*8+3][c]=fmaxf(a3+b,0.f);
    scratch[rg*8+4][c]=fmaxf(a4+b,0.f); scratch[rg*8+5][c]=fmaxf(a5+b,0.f);
    scratch[rg*8+6][c]=fmaxf(a6+b,0.f); scratch[rg*8+7][c]=fmaxf(a7+b,0.f);
  }
  {
    int c = tid & 63, rg = tid >> 6;
    float a0=0.f,a1=0.f,a2=0.f,a3=0.f;
#pragma unroll 2
    for (int k = 0; k < DST; ++k) {
      float wv = b1_k[k * 64 + c];
      a0 += s_lds[rg*4+0][k]*wv; a1 += s_lds[rg*4+1][k]*wv;
      a2 += s_lds[rg*4+2][k]*wv; a3 += s_lds[rg*4+3][k]*wv;
    }
    float b = b1_b[c];
    b1l[rg*4+0][c]=a0+b; b1l[rg*4+1][c]=a1+b; b1l[rg*4+2][c]=a2+b; b1l[rg*4+3][c]=a3+b;
  }
  __syncthreads();
  {
    int c = tid & 127, rg = tid >> 7;
    float a0=0.f,a1=0.f,a2=0.f,a3=0.f,a4=0.f,a5=0.f,a6=0.f,a7=0.f;
#pragma unroll 2
    for (int k = 0; k < DST; ++k) {
      float wv = hw1_k2[k * 128 + c];
      a0 += scratch[rg*8+0][k]*wv; a1 += scratch[rg*8+1][k]*wv;
      a2 += scratch[rg*8+2][k]*wv; a3 += scratch[rg*8+3][k]*wv;
      a4 += scratch[rg*8+4][k]*wv; a5 += scratch[rg*8+5][k]*wv;
      a6 += scratch[rg*8+6][k]*wv; a7 += scratch[rg*8+7][k]*wv;
    }
    float b = hw1_b2[c];
    w1l[rg*8+0][c]=fabsf(a0+b); w1l[rg*8+1][c]=fabsf(a1+b);
    w1l[rg*8+2][c]=fabsf(a2+b); w1l[rg*8+3][c]=fabsf(a3+b);
    w1l[rg*8+4][c]=fabsf(a4+b); w1l[rg*8+5][c]=fabsf(a5+b);
    w1l[rg*8+6][c]=fabsf(a6+b); w1l[rg*8+7][c]=fabsf(a7+b);
  }
  {
    int c = tid & 63, rg = tid >> 6;
    float a0=0.f,a1=0.f,a2=0.f,a3=0.f;
#pragma unroll 2
    for (int k = 0; k < DST; ++k) {
      float wv = hb2_k1[k * 64 + c];
      a0 += s_lds[rg*4+0][k]*wv; a1 += s_lds[rg*4+1][k]*wv;
      a2 += s_lds[rg*4+2][k]*wv; a3 += s_lds[rg*4+3][k]*wv;
    }
    float b = hb2_b1[c];
    scratch2[rg*4+0][c]=fmaxf(a0+b,0.f); scratch2[rg*4+1][c]=fmaxf(a1+b,0.f);
    scratch2[rg*4+2][c]=fmaxf(a2+b,0.f); scratch2[rg*4+3][c]=fmaxf(a3+b,0.f);
  }
  __syncthreads();
  {
    int c = tid & 127, rg = tid >> 7;
    float a0=0.f,a1=0.f,a2=0.f,a3=0.f,a4=0.f,a5=0.f,a6=0.f,a7=0.f;
#pragma unroll 2
    for (int k = 0; k < DST; ++k) {
      float wv = hw2_k1[k * 128 + c];
      a0 += s_lds[rg*8+0][k]*wv; a1 += s_lds[rg*8+1][k]*wv;
      a2 += s_lds[rg*8+2][k]*wv; a3 += s_lds[rg*8+3][k]*wv;
      a4 += s_lds[rg*8+4][k]*wv; a5 += s_lds[rg*8+5][k]*wv;
      a6 += s_lds[rg*8+6][k]*wv; a7 += s_lds[rg*8+7][k]*wv;
    }
    float b = hw2_b1[c];
    scratch[rg*8+0][c]=fmaxf(a0+b,0.f); scratch[rg*8+1][c]=fmaxf(a1+b,0.f);
    scratch[rg*8+2][c]=fmaxf(a2+b,0.f); scratch[rg*8+3][c]=fmaxf(a3+b,0.f);
    scratch[rg*8+4][c]=fmaxf(a4+b,0.f); scratch[rg*8+5][c]=fmaxf(a5+b,0.f);
    scratch[rg*8+6][c]=fmaxf(a6+b,0.f); scratch[rg*8+7][c]=fmaxf(a7+b,0.f);
  }
  if (tid < FB_RPB * S_SAMP) {
    float v = scratch2[r][sl]      * hb2_k2[sl]
            + scratch2[r][sl + 16] * hb2_k2[sl + 16]
            + scratch2[r][sl + 32] * hb2_k2[sl + 32]
            + scratch2[r][sl + 48] * hb2_k2[sl + 48];
    v += __shfl_down(v, 8, 16); v += __shfl_down(v, 4, 16);
    v += __shfl_down(v, 2, 16); v += __shfl_down(v, 1, 16);
    if (sl == 0) b2l[r] = v + hb2_b2[0];
  }
  __syncthreads();
  {
    int c = tid & 63, rg = tid >> 6;
    float a0=0.f,a1=0.f,a2=0.f,a3=0.f;
#pragma unroll 2
    for (int k = 0; k < DST; ++k) {
      float wv = hw2_k2[k * 64 + c];
      a0 += scratch[rg*4+0][k]*wv; a1 += scratch[rg*4+1][k]*wv;
      a2 += scratch[rg*4+2][k]*wv; a3 += scratch[rg*4+3][k]*wv;
    }
    float b = hw2_b2[c];
    w2l[rg*4+0][c]=fabsf(a0+b); w2l[rg*4+1][c]=fabsf(a1+b);
    w2l[rg*4+2][c]=fabsf(a2+b); w2l[rg*4+3][c]=fabsf(a3+b);
  }
  __syncthreads();
  {
    float cn[N_AG], qv[N_AG], y[N_AG];
#pragma unroll
    for (int a = 0; a < N_AG; ++a) { cn[a]=cnred[r][sl][a]; qv[a]=qlf[r][a]; y[a]=0.f; }
#pragma unroll 4
    for (int e = 0; e < E_DIM; e += 4) {
      const float4 wa  = ld4(&w1l[r][e]);
      const float4 wb  = ld4(&w1l[r][64 + e]);
      const float4 bb  = ld4(&b1l[r][e]);
      const float4 w2v = ld4(&w2l[r][e]);
#pragma unroll
      for (int a = 0; a < N_AG; ++a) {
        float h;
        h = fmaf(cn[a], wa.x, fmaf(qv[a], wb.x, bb.x));
        y[a] = fmaf((h > 0.f) ? h : (__expf(h) - 1.f), w2v.x, y[a]);
        h = fmaf(cn[a], wa.y, fmaf(qv[a], wb.y, bb.y));
        y[a] = fmaf((h > 0.f) ? h : (__expf(h) - 1.f), w2v.y, y[a]);
        h = fmaf(cn[a], wa.z, fmaf(qv[a], wb.z, bb.z));
        y[a] = fmaf((h > 0.f) ? h : (__expf(h) - 1.f), w2v.z, y[a]);
        h = fmaf(cn[a], wa.w, fmaf(qv[a], wb.w, bb.w));
        y[a] = fmaf((h > 0.f) ? h : (__expf(h) - 1.f), w2v.w, y[a]);
      }
    }
    const float b2v = b2l[r];
#pragma unroll
    for (int a = 0; a < N_AG; ++a) cnred[r][sl][a] = fabsf(y[a] + b2v);
  }
  __syncthreads();
  if (tid < FB_RPB * N_AG) {
    const int a = tid >> 4, rr = tid & 15;
    float acc = 0.f;
#pragma unroll
    for (int ss = 0; ss < S_SAMP; ++ss) acc += cnred[rr][ss][a];
    out[a * TB + row0 + rr] = acc * (1.0f / (float)S_SAMP);
  }
}

extern "C" void kernel_launch(void* const* d_in, const int* in_sizes, int n_in,
                              void* d_out, int out_size, void* d_ws, size_t ws_size,
                              hipStream_t stream) {
  const float* q_vals = (const float*)d_in[0];
  const float* states = (const float*)d_in[1];
  const float* hw1_k1 = (const float*)d_in[2];
  const float* hw1_b1 = (const float*)d_in[3];
  const float* hw1_k2 = (const float*)d_in[4];
  const float* hw1_b2 = (const float*)d_in[5];
  const float* b1_k   = (const float*)d_in[6];
  const float* b1_b   = (const float*)d_in[7];
  const float* hw2_k1 = (const float*)d_in[8];
  const float* hw2_b1 = (const float*)d_in[9];
  const float* hw2_k2 = (const float*)d_in[10];
  const float* hw2_b2 = (const float*)d_in[11];
  const float* hb2_k1 = (const float*)d_in[12];
  const float* hb2_b1 = (const float*)d_in[13];
  const float* hb2_k2 = (const float*)d_in[14];
  const float* hb2_b2 = (const float*)d_in[15];
  float* out = (float*)d_out;

  const size_t need = (size_t)WT_ELEMS * sizeof(unsigned short);
  if (ws_size >= need) {
    unsigned short* wt = (unsigned short*)d_ws;
    wt_transpose<<<dim3(72), 256, 0, stream>>>(
        hw1_k1, hw2_k1, hw1_k2, b1_k, hb2_k1, hw2_k2, wt);
    alpha_mfma2<<<dim3(TB / RPB), 256, 0, stream>>>(
        q_vals, states, hw1_b1, hw1_b2, b1_b, hw2_b1, hw2_b2, hb2_b1,
        hb2_k2, hb2_b2, wt, out);
  } else {
    alpha_fused2<<<dim3(TB / FB_RPB), 256, 0, stream>>>(
        q_vals, states, hw1_k1, hw1_b1, hw1_k2, hw1_b2, b1_k, b1_b,
        hw2_k1, hw2_b1, hw2_k2, hw2_b2, hb2_k1, hb2_b1, hb2_k2, hb2_b2, out);
  }
}

// Round 15
// 33.990 us; speedup vs baseline: 1.3865x; 1.2180x over previous
//
#include <hip/hip_runtime.h>
#include <stdint.h>

// Problem constants (from reference)
#define N_AG   8
#define S_SAMP 16
#define TB     8192      // T*B
#define DST    128       // D_STATE
#define E_DIM  64

#define RPB    16        // rows per block -> 512 blocks, 512 threads (8 waves)
#define CN_STR 9         // cn stride: spreads 16 samples over banks

// WT layout in d_ws (bf16 element offsets): [n][k] row-major, k-stride 128
#define WT1K1  0         // hw1_k1^T  [128][128]
#define WT2K1  16384     // hw2_k1^T  [128][128]
#define WT1K2  32768     // hw1_k2^T  [128][128]
#define WTM3   49152     // rows 0..63 = b1_k^T, rows 64..127 = hb2_k1^T
#define WT2K2  65536     // hw2_k2^T  [64][128]
#define WT_ELEMS 73728   // total bf16 elements (147456 B)

typedef __attribute__((ext_vector_type(8))) short  short8v;   // 8 bf16 = 4 VGPR
typedef __attribute__((ext_vector_type(4))) float  float4v;   // C/D frag

__device__ __forceinline__ float4 ld4(const float* p) { return *(const float4*)p; }

// f32 -> bf16 round-to-nearest-even
__device__ __forceinline__ unsigned short f2bf(float f) {
  uint32_t x = __float_as_uint(f);
  return (unsigned short)((x + 0x7FFFu + ((x >> 16) & 1u)) >> 16);
}
__device__ __forceinline__ uint32_t pk2(float lo, float hi) {
  return (uint32_t)f2bf(lo) | ((uint32_t)f2bf(hi) << 16);
}

// ---------------- JAX threefry2x32 (20 rounds) ----------------
__device__ __forceinline__ uint2 tf2x32(uint32_t k0, uint32_t k1,
                                        uint32_t c0, uint32_t c1) {
  uint32_t ks2 = k0 ^ k1 ^ 0x1BD11BDAu;
  uint32_t x0 = c0 + k0, x1 = c1 + k1;
#define TFR(r) { x0 += x1; x1 = (x1 << (r)) | (x1 >> (32 - (r))); x1 ^= x0; }
  TFR(13) TFR(15) TFR(26) TFR(6)
  x0 += k1;  x1 += ks2 + 1u;
  TFR(17) TFR(29) TFR(16) TFR(24)
  x0 += ks2; x1 += k0 + 2u;
  TFR(13) TFR(15) TFR(26) TFR(6)
  x0 += k0;  x1 += k1 + 3u;
  TFR(17) TFR(29) TFR(16) TFR(24)
  x0 += k1;  x1 += ks2 + 4u;
  TFR(13) TFR(15) TFR(26) TFR(6)
  x0 += ks2; x1 += k0 + 5u;
#undef TFR
  return make_uint2(x0, x1);
}

// Swizzled bf16 LDS tile helpers (R9-verified): rows 256B, byte ^= (row&7)<<4
__device__ __forceinline__ short8v rdfrag(const unsigned short* base, int row, int ks, int lhi) {
  const int b = (row * 256 + ks * 64 + lhi * 16) ^ ((row & 7) << 4);
  return *(const short8v*)((const char*)base + b);
}
__device__ __forceinline__ void wrbf(unsigned short* pan, int r, int c, float v) {
  const int b = (r * 256 + c * 2) ^ ((r & 7) << 4);
  *(unsigned short*)((char*)pan + b) = f2bf(v);
}
// B-fragment directly from global pre-transposed bf16 (R10-verified)
__device__ __forceinline__ short8v gfrag(const unsigned short* wt, int n, int ks, int lhi) {
  return *(const short8v*)(wt + (n << 7) + ks * 32 + lhi * 8);
}

// ========== K0: transpose+convert all weights to bf16 [n][k] in d_ws (R10-verified) ==========
__global__ __launch_bounds__(256)
void wt_transpose(const float* __restrict__ hw1_k1, const float* __restrict__ hw2_k1,
                  const float* __restrict__ hw1_k2, const float* __restrict__ b1_k,
                  const float* __restrict__ hb2_k1, const float* __restrict__ hw2_k2,
                  unsigned short* __restrict__ wt)
{
  __shared__ float t[32][33];
  const int b = blockIdx.x;
  const float* src; int ldn, t0, dstbase;
  if (b < 16)      { src = hw1_k1; ldn = 128; t0 = b;      dstbase = WT1K1; }
  else if (b < 32) { src = hw2_k1; ldn = 128; t0 = b - 16; dstbase = WT2K1; }
  else if (b < 48) { src = hw1_k2; ldn = 128; t0 = b - 32; dstbase = WT1K2; }
  else if (b < 56) { src = b1_k;   ldn = 64;  t0 = b - 48; dstbase = WTM3; }
  else if (b < 64) { src = hb2_k1; ldn = 64;  t0 = b - 56; dstbase = WTM3 + 64 * 128; }
  else             { src = hw2_k2; ldn = 64;  t0 = b - 64; dstbase = WT2K2; }
  const int kt = t0 & 3, nt = t0 >> 2;
  const int tid = threadIdx.x;
  {
    const int c = tid & 31;
    for (int r = tid >> 5; r < 32; r += 8)
      t[r][c] = src[(size_t)(kt * 32 + r) * ldn + nt * 32 + c];
  }
  __syncthreads();
  {
    const int c2 = tid & 15;
    for (int n = tid >> 4; n < 32; n += 16) {
      const uint32_t v = pk2(t[2 * c2][n], t[2 * c2 + 1][n]);
      *(uint32_t*)&wt[dstbase + (nt * 32 + n) * 128 + kt * 32 + 2 * c2] = v;
    }
  }
}

// ========================= Main fused kernel =========================
// R15: RPB=16 with 512 threads (8 waves). Full M=16 MFMA tiles (no lhi<2
// waste); 8 waves x 16-col tiles cover 128 cols; RNG on tid<256 = waves 0-3
// = one RNG wave per SIMD (balanced). All numerics verbatim from the
// R10/R12/R14-verified build; every LDS slot single-writer.
__global__ __launch_bounds__(512, 4)
void alpha_mfma3(const float* __restrict__ q_vals,   // (8, 8192)
                 const float* __restrict__ states,   // (8192, 128)
                 const float* __restrict__ hw1_b1, const float* __restrict__ hw1_b2,
                 const float* __restrict__ b1_b,   const float* __restrict__ hw2_b1,
                 const float* __restrict__ hw2_b2, const float* __restrict__ hb2_b1,
                 const float* __restrict__ hb2_k2, const float* __restrict__ hb2_b2,
                 const unsigned short* __restrict__ wt,
                 float* __restrict__ out)            // (8, 8192)
{
  __shared__ unsigned short xbf[RPB * 128];     // X bf16 swz            4 KB
  __shared__ unsigned short h1bf[RPB * 128];    // relu(h1) bf16 swz     4 KB
  __shared__ unsigned short h2bf[RPB * 128];    // relu(h2) bf16 swz     4 KB
  __shared__ float w1l[RPB][132];               // |w1| f32            8.4 KB
  __shared__ float b1l[RPB][68];                //                     4.3 KB
  __shared__ float w2l[RPB][68];                //                     4.3 KB
  __shared__ float hbl[RPB][68];                //                     4.3 KB
  __shared__ float b2l[RPB];
  __shared__ float ql[RPB][N_AG];
  __shared__ float cn_l[RPB][S_SAMP][CN_STR];   // cn then |y|         9.2 KB

  const int tid  = threadIdx.x;
  const int row0 = blockIdx.x * RPB;
  const int lane = tid & 63;
  const int wv   = tid >> 6;        // wave 0..7
  const int lrow = lane & 15;       // A-row / B-col within a 16-tile
  const int lhi  = lane >> 4;       // k-group; C rows lhi*4+j (ALL 16 used)

  // ---- P0: X f32 -> bf16 swz LDS (16 rows, 512 float4 = 1/thread); q load ----
  {
    const int r = tid >> 5, k0 = (tid & 31) * 4;
    const float4 v = ld4(&states[(size_t)(row0 + r) * DST + k0]);
    const int b = (r * 256 + k0 * 2) ^ ((r & 7) << 4);
    *(uint32_t*)((char*)xbf + b)     = pk2(v.x, v.y);
    *(uint32_t*)((char*)xbf + b + 4) = pk2(v.z, v.w);
  }
  if (tid < RPB * N_AG) {
    const int rr = tid >> 3, a = tid & 7;
    ql[rr][a] = q_vals[a * TB + row0 + rr];
  }
  __syncthreads();

  // ---- RNG: one (row, sample) per thread, tid<256 = waves 0-3 (verified chain) ----
  if (tid < RPB * S_SAMP) {
    const int r  = tid >> 4;
    const int sl = tid & 15;
    const uint32_t j = (uint32_t)(row0 + r) * (uint32_t)S_SAMP + (uint32_t)sl;
    uint2 kj  = tf2x32(0u, 42u, 0u, j);       // partitionable split of key(42)
    uint2 sub = tf2x32(kj.x, kj.y, 0u, 1u);   // subkey = split(key_j)[1]
    uint32_t K[N_AG];
#pragma unroll
    for (int i = 0; i < N_AG; ++i) {
      uint2 b = tf2x32(sub.x, sub.y, 0u, (uint32_t)i);
      K[i] = b.x ^ b.y;
    }
    int posa[N_AG];
#pragma unroll
    for (int i = 0; i < N_AG; ++i) {
      int rank = 0;
#pragma unroll
      for (int m = 0; m < N_AG; ++m)
        rank += (K[m] < K[i]) || (K[m] == K[i] && m < i);
      posa[rank] = i;
    }
#pragma unroll
    for (int a = 0; a < N_AG; ++a) {
      const int pa = posa[a];
      float cs = 0.f;
#pragma unroll
      for (int a2 = 0; a2 < N_AG; ++a2)
        cs += (posa[a2] < pa) ? ql[r][a2] : 0.f;
      cn_l[r][sl][a] = cs / (float)max(pa, 1);
    }
  }

  // ===== M1: h1 = relu(X @ hw1_k1 + b) -> h1bf  (8 waves x 16 cols) =====
  {
    float4v a0 = {0.f,0.f,0.f,0.f};
    const int c = wv * 16 + lrow;
#pragma unroll
    for (int ks = 0; ks < 4; ++ks) {
      const short8v af = rdfrag(xbf, lrow, ks, lhi);
      a0 = __builtin_amdgcn_mfma_f32_16x16x32_bf16(af, gfrag(wt + WT1K1, c, ks, lhi), a0, 0, 0, 0);
    }
    const float bv = hw1_b1[c];
#pragma unroll
    for (int j = 0; j < 4; ++j)
      wrbf(h1bf, lhi * 4 + j, c, fmaxf(a0[j] + bv, 0.f));
  }

  // ===== M2: h2 = relu(X @ hw2_k1 + b) -> h2bf =====
  {
    float4v a0 = {0.f,0.f,0.f,0.f};
    const int c = wv * 16 + lrow;
#pragma unroll
    for (int ks = 0; ks < 4; ++ks) {
      const short8v af = rdfrag(xbf, lrow, ks, lhi);
      a0 = __builtin_amdgcn_mfma_f32_16x16x32_bf16(af, gfrag(wt + WT2K1, c, ks, lhi), a0, 0, 0, 0);
    }
    const float bv = hw2_b1[c];
#pragma unroll
    for (int j = 0; j < 4; ++j)
      wrbf(h2bf, lhi * 4 + j, c, fmaxf(a0[j] + bv, 0.f));
  }

  // ===== M3: cols 0..63 -> b1 = X@b1_k + b; 64..127 -> hb = relu(X@hb2_k1 + b) =====
  {
    float4v a0 = {0.f,0.f,0.f,0.f};
    const int c = wv * 16 + lrow;
#pragma unroll
    for (int ks = 0; ks < 4; ++ks) {
      const short8v af = rdfrag(xbf, lrow, ks, lhi);
      a0 = __builtin_amdgcn_mfma_f32_16x16x32_bf16(af, gfrag(wt + WTM3, c, ks, lhi), a0, 0, 0, 0);
    }
    if (c < 64) {
      const float bv = b1_b[c];
#pragma unroll
      for (int j = 0; j < 4; ++j)
        b1l[lhi * 4 + j][c] = a0[j] + bv;
    } else {
      const float bv = hb2_b1[c - 64];
#pragma unroll
      for (int j = 0; j < 4; ++j)
        hbl[lhi * 4 + j][c - 64] = fmaxf(a0[j] + bv, 0.f);
    }
  }
  __syncthreads();   // h1bf/h2bf/b1l/hbl/cn_l now visible

  // ---- b2[r] = hb . hb2_k2 + b (16 rows; 16-lane partial + shuffle) ----
  if (tid < RPB * S_SAMP) {
    const int r = tid >> 4, sl = tid & 15;
    float v = hbl[r][sl]      * hb2_k2[sl]
            + hbl[r][sl + 16] * hb2_k2[sl + 16]
            + hbl[r][sl + 32] * hb2_k2[sl + 32]
            + hbl[r][sl + 48] * hb2_k2[sl + 48];
    v += __shfl_down(v, 8, 16); v += __shfl_down(v, 4, 16);
    v += __shfl_down(v, 2, 16); v += __shfl_down(v, 1, 16);
    if (sl == 0) b2l[r] = v + hb2_b2[0];
  }

  // ===== M4: w1 = |h1 @ hw1_k2 + b| -> w1l (f32) =====
  {
    float4v a0 = {0.f,0.f,0.f,0.f};
    const int c = wv * 16 + lrow;
#pragma unroll
    for (int ks = 0; ks < 4; ++ks) {
      const short8v af = rdfrag(h1bf, lrow, ks, lhi);
      a0 = __builtin_amdgcn_mfma_f32_16x16x32_bf16(af, gfrag(wt + WT1K2, c, ks, lhi), a0, 0, 0, 0);
    }
    const float bv = hw1_b2[c];
#pragma unroll
    for (int j = 0; j < 4; ++j)
      w1l[lhi * 4 + j][c] = fabsf(a0[j] + bv);
  }

  // ===== M5: w2 = |h2 @ hw2_k2 + b| (waves 0-3; 4 col-tiles) =====
  if (wv < 4) {
    float4v a0 = {0.f,0.f,0.f,0.f};
    const int c = wv * 16 + lrow;
#pragma unroll
    for (int ks = 0; ks < 4; ++ks) {
      const short8v af = rdfrag(h2bf, lrow, ks, lhi);
      a0 = __builtin_amdgcn_mfma_f32_16x16x32_bf16(af, gfrag(wt + WT2K2, c, ks, lhi), a0, 0, 0, 0);
    }
    const float bv = hw2_b2[c];
#pragma unroll
    for (int j = 0; j < 4; ++j)
      w2l[lhi * 4 + j][c] = fabsf(a0[j] + bv);
  }
  __syncthreads();   // w1l/w2l/b2l visible

  // ===== Main: thread = (r in 16, sl in 16, agent-half in 2); all 512 active =====
  {
    const int sl  = tid & 15;
    const int r   = (tid >> 4) & 15;
    const int a0i = (tid >> 8) * 4;   // agents a0i..a0i+3
    float cn[4], qv[4], y[4];
#pragma unroll
    for (int jj = 0; jj < 4; ++jj) {
      cn[jj] = cn_l[r][sl][a0i + jj];
      qv[jj] = ql[r][a0i + jj];
      y[jj]  = 0.f;
    }
#pragma unroll 4
    for (int e = 0; e < E_DIM; e += 4) {
      const float4 wa  = ld4(&w1l[r][e]);
      const float4 wb  = ld4(&w1l[r][64 + e]);
      const float4 bb  = ld4(&b1l[r][e]);
      const float4 w2v = ld4(&w2l[r][e]);
#pragma unroll
      for (int jj = 0; jj < 4; ++jj) {
        float h;
        h = fmaf(cn[jj], wa.x, fmaf(qv[jj], wb.x, bb.x));
        y[jj] = fmaf((h > 0.f) ? h : (__expf(h) - 1.f), w2v.x, y[jj]);
        h = fmaf(cn[jj], wa.y, fmaf(qv[jj], wb.y, bb.y));
        y[jj] = fmaf((h > 0.f) ? h : (__expf(h) - 1.f), w2v.y, y[jj]);
        h = fmaf(cn[jj], wa.z, fmaf(qv[jj], wb.z, bb.z));
        y[jj] = fmaf((h > 0.f) ? h : (__expf(h) - 1.f), w2v.z, y[jj]);
        h = fmaf(cn[jj], wa.w, fmaf(qv[jj], wb.w, bb.w));
        y[jj] = fmaf((h > 0.f) ? h : (__expf(h) - 1.f), w2v.w, y[jj]);
      }
    }
    const float b2v = b2l[r];
#pragma unroll
    for (int jj = 0; jj < 4; ++jj)
      cn_l[r][sl][a0i + jj] = fabsf(y[jj] + b2v);   // own slots only
  }
  __syncthreads();

  // ---- Reduce over samples; rr = tid&15 so 16 consecutive rows coalesce ----
  if (tid < RPB * N_AG) {
    const int rr = tid & 15, a = tid >> 4;
    float acc = 0.f;
#pragma unroll
    for (int ss = 0; ss < S_SAMP; ++ss) acc += cn_l[rr][ss][a];
    out[a * TB + row0 + rr] = acc * (1.0f / (float)S_SAMP);
  }
}

// ============ Fallback (R4-structure, proven): used only if ws too small ============
#define FB_RPB 16
#define FB_H_PAD 132
#define FB_E_PAD 68
__global__ __launch_bounds__(256)
void alpha_fused2(const float* __restrict__ q_vals, const float* __restrict__ states,
                  const float* __restrict__ hw1_k1, const float* __restrict__ hw1_b1,
                  const float* __restrict__ hw1_k2, const float* __restrict__ hw1_b2,
                  const float* __restrict__ b1_k,   const float* __restrict__ b1_b,
                  const float* __restrict__ hw2_k1, const float* __restrict__ hw2_b1,
                  const float* __restrict__ hw2_k2, const float* __restrict__ hw2_b2,
                  const float* __restrict__ hb2_k1, const float* __restrict__ hb2_b1,
                  const float* __restrict__ hb2_k2, const float* __restrict__ hb2_b2,
                  float* __restrict__ out)
{
  __shared__ float s_lds[FB_RPB][DST];
  __shared__ float scratch[FB_RPB][FB_H_PAD];
  __shared__ float scratch2[FB_RPB][FB_E_PAD];
  __shared__ float w1l[FB_RPB][FB_H_PAD];
  __shared__ float b1l[FB_RPB][FB_E_PAD];
  __shared__ float w2l[FB_RPB][FB_E_PAD];
  __shared__ float b2l[FB_RPB];
  __shared__ float qlf[FB_RPB][N_AG];
  __shared__ float cnred[FB_RPB][S_SAMP][N_AG];
  const int tid = threadIdx.x;
  const int row0 = blockIdx.x * FB_RPB;
  const int r = tid >> 4, sl = tid & 15;
  {
    const float4* src = reinterpret_cast<const float4*>(states + (size_t)row0 * DST);
    reinterpret_cast<float4*>(&s_lds[0][0])[tid]       = src[tid];
    reinterpret_cast<float4*>(&s_lds[0][0])[tid + 256] = src[tid + 256];
  }
  if (tid < FB_RPB * N_AG) {
    const int rr = tid >> 3, a = tid & 7;
    qlf[rr][a] = q_vals[a * TB + row0 + rr];
  }
  __syncthreads();
  {
    const uint32_t j = (uint32_t)(row0 + r) * (uint32_t)S_SAMP + (uint32_t)sl;
    uint2 kj = tf2x32(0u, 42u, 0u, j);
    uint2 sub = tf2x32(kj.x, kj.y, 0u, 1u);
    uint32_t K[N_AG];
#pragma unroll
    for (int i = 0; i < N_AG; ++i) { uint2 b = tf2x32(sub.x, sub.y, 0u, (uint32_t)i); K[i] = b.x ^ b.y; }
    int posa[N_AG];
#pragma unroll
    for (int i = 0; i < N_AG; ++i) {
      int rank = 0;
#pragma unroll
      for (int m = 0; m < N_AG; ++m) rank += (K[m] < K[i]) || (K[m] == K[i] && m < i);
      posa[rank] = i;
    }
#pragma unroll
    for (int a = 0; a < N_AG; ++a) {
      const int pa = posa[a];
      float cs = 0.f;
#pragma unroll
      for (int a2 = 0; a2 < N_AG; ++a2) cs += (posa[a2] < pa) ? qlf[r][a2] : 0.f;
      cnred[r][sl][a] = cs / (float)max(pa, 1);
    }
  }
  {
    int c = tid & 127, rg = tid >> 7;
    float a0=0.f,a1=0.f,a2=0.f,a3=0.f,a4=0.f,a5=0.f,a6=0.f,a7=0.f;
#pragma unroll 2
    for (int k = 0; k < DST; ++k) {
      float wv = hw1_k1[k * 128 + c];
      a0 += s_lds[rg*8+0][k]*wv; a1 += s_lds[rg*8+1][k]*wv;
      a2 += s_lds[rg*8+2][k]*wv; a3 += s_lds[rg*8+3][k]*wv;
      a4 += s_lds[rg*8+4][k]*wv; a5 += s_lds[rg*8+5][k]*wv;
      a6 += s_lds[rg*8+6][k]*wv; a7 += s_lds[rg*8+7][k]*wv;
    }
    float b = hw1_b1[c];
    scratch[rg*8+0][c]=fmaxf(a0+b,0.f); scratch[rg*8+1][c]=fmaxf(a1+b,0.f);
    scratch[rg*8+2][c]=fmaxf(a2+b,0.f); scratch[rg*8+3][c]=fmaxf(a3+b,0.f);
    scratch[rg*8+4][c]=fmaxf(a4+b,0.f); scratch[rg*8+5][c]=fmaxf(a5+b,0.f);
    scratch[rg*8+6][c]=fmaxf(a6+b,0.f); scratch[rg*8+7][c]=fmaxf(a7+b,0.f);
  }
  {
    int c = tid & 63, rg = tid >> 6;
    float a0=0.f,a1=0.f,a2=0.f,a3=0.f;
#pragma unroll 2
    for (int k = 0; k < DST; ++k) {
      float wv = b1_k[k * 64 + c];
      a0 += s_lds[rg*4+0][k]*wv; a1 += s_lds[rg*4+1][k]*wv;
      a2 += s_lds[rg*4+2][k]*wv; a3 += s_lds[rg*4+3][k]*wv;
    }
    float b = b1_b[c];
    b1l[rg*4+0][c]=a0+b; b1l[rg*4+1][c]=a1+b; b1l[rg*4+2][c]=a2+b; b1l[rg*4+3][c]=a3+b;
  }
  __syncthreads();
  {
    int c = tid & 127, rg = tid >> 7;
    float a0=0.f,a1=0.f,a2=0.f,a3=0.f,a4=0.f,a5=0.f,a6=0.f,a7=0.f;
#pragma unroll 2
    for (int k = 0; k < DST; ++k) {
      float wv = hw1_k2[k * 128 + c];
      a0 += scratch[rg*8+0][k]*wv; a1 += scratch[rg*8+1][k]*wv;
      a2 += scratch[rg*8+2][k]*wv; a3 += scratch[rg*8+3][k]*wv;
      a4 += scratch[rg*8+4][k]*wv; a5 += scratch[rg*8+5][k]*wv;
      a6 += scratch[rg*8+6][k]*wv; a7 += scratch[rg*8+7][k]*wv;
    }
    float b = hw1_b2[c];
    w1l[rg*8+0][c]=fabsf(a0+b); w1l[rg*8+1][c]=fabsf(a1+b);
    w1l[rg*8+2][c]=fabsf(a2+b); w1l[rg*8+3][c]=fabsf(a3+b);
    w1l[rg*8+4][c]=fabsf(a4+b); w1l[rg*8+5][c]=fabsf(a5+b);
    w1l[rg*8+6][c]=fabsf(a6+b); w1l[rg*8+7][c]=fabsf(a7+b);
  }
  {
    int c = tid & 63, rg = tid >> 6;
    float a0=0.f,a1=0.f,a2=0.f,a3=0.f;
#pragma unroll 2
    for (int k = 0; k < DST; ++k) {
      float wv = hb2_k1[k * 64 + c];
      a0 += s_lds[rg*4+0][k]*wv; a1 += s_lds[rg*4+1][k]*wv;
      a2 += s_lds[rg*4+2][k]*wv; a3 += s_lds[rg*4+3][k]*wv;
    }
    float b = hb2_b1[c];
    scratch2[rg*4+0][c]=fmaxf(a0+b,0.f); scratch2[rg*4+1][c]=fmaxf(a1+b,0.f);
    scratch2[rg*4+2][c]=fmaxf(a2+b,0.f); scratch2[rg*4+3][c]=fmaxf(a3+b,0.f);
  }
  __syncthreads();
  {
    int c = tid & 127, rg = tid >> 7;
    float a0=0.f,a1=0.f,a2=0.f,a3=0.f,a4=0.f,a5=0.f,a6=0.f,a7=0.f;
#pragma unroll 2
    for (int k = 0; k < DST; ++k) {
      float wv = hw2_k1[k * 128 + c];
      a0 += s_lds[rg*8+0][k]*wv; a1 += s_lds[rg*8+1][k]*wv;
      a2 += s_lds[rg*8+2][k]*wv; a3 += s_lds[rg*8+3][k]*wv;
      a4 += s_lds[rg*8+4][k]*wv; a5 += s_lds[rg*8+5][k]*wv;
      a6 += s_lds[rg*8+6][k]*wv; a7 += s_lds[rg*8+7][k]*wv;
    }
    float b = hw2_b1[c];
    scratch[rg*8+0][c]=fmaxf(a0+b,0.f); scratch[rg*8+1][c]=fmaxf(a1+b,0.f);
    scratch[rg*8+2][c]=fmaxf(a2+b,0.f); scratch[rg*8+3][c]=fmaxf(a3+b,0.f);
    scratch[rg*8+4][c]=fmaxf(a4+b,0.f); scratch[rg*8+5][c]=fmaxf(a5+b,0.f);
    scratch[rg*8+6][c]=fmaxf(a6+b,0.f); scratch[rg*8+7][c]=fmaxf(a7+b,0.f);
  }
  if (tid < FB_RPB * S_SAMP) {
    float v = scratch2[r][sl]      * hb2_k2[sl]
            + scratch2[r][sl + 16] * hb2_k2[sl + 16]
            + scratch2[r][sl + 32] * hb2_k2[sl + 32]
            + scratch2[r][sl + 48] * hb2_k2[sl + 48];
    v += __shfl_down(v, 8, 16); v += __shfl_down(v, 4, 16);
    v += __shfl_down(v, 2, 16); v += __shfl_down(v, 1, 16);
    if (sl == 0) b2l[r] = v + hb2_b2[0];
  }
  __syncthreads();
  {
    int c = tid & 63, rg = tid >> 6;
    float a0=0.f,a1=0.f,a2=0.f,a3=0.f;
#pragma unroll 2
    for (int k = 0; k < DST; ++k) {
      float wv = hw2_k2[k * 64 + c];
      a0 += scratch[rg*4+0][k]*wv; a1 += scratch[rg*4+1][k]*wv;
      a2 += scratch[rg*4+2][k]*wv; a3 += scratch[rg*4+3][k]*wv;
    }
    float b = hw2_b2[c];
    w2l[rg*4+0][c]=fabsf(a0+b); w2l[rg*4+1][c]=fabsf(a1+b);
    w2l[rg*4+2][c]=fabsf(a2+b); w2l[rg*4+3][c]=fabsf(a3+b);
  }
  __syncthreads();
  {
    float cn[N_AG], qv[N_AG], y[N_AG];
#pragma unroll
    for (int a = 0; a < N_AG; ++a) { cn[a]=cnred[r][sl][a]; qv[a]=qlf[r][a]; y[a]=0.f; }
#pragma unroll 4
    for (int e = 0; e < E_DIM; e += 4) {
      const float4 wa  = ld4(&w1l[r][e]);
      const float4 wb  = ld4(&w1l[r][64 + e]);
      const float4 bb  = ld4(&b1l[r][e]);
      const float4 w2v = ld4(&w2l[r][e]);
#pragma unroll
      for (int a = 0; a < N_AG; ++a) {
        float h;
        h = fmaf(cn[a], wa.x, fmaf(qv[a], wb.x, bb.x));
        y[a] = fmaf((h > 0.f) ? h : (__expf(h) - 1.f), w2v.x, y[a]);
        h = fmaf(cn[a], wa.y, fmaf(qv[a], wb.y, bb.y));
        y[a] = fmaf((h > 0.f) ? h : (__expf(h) - 1.f), w2v.y, y[a]);
        h = fmaf(cn[a], wa.z, fmaf(qv[a], wb.z, bb.z));
        y[a] = fmaf((h > 0.f) ? h : (__expf(h) - 1.f), w2v.z, y[a]);
        h = fmaf(cn[a], wa.w, fmaf(qv[a], wb.w, bb.w));
        y[a] = fmaf((h > 0.f) ? h : (__expf(h) - 1.f), w2v.w, y[a]);
      }
    }
    const float b2v = b2l[r];
#pragma unroll
    for (int a = 0; a < N_AG; ++a) cnred[r][sl][a] = fabsf(y[a] + b2v);
  }
  __syncthreads();
  if (tid < FB_RPB * N_AG) {
    const int a = tid >> 4, rr = tid & 15;
    float acc = 0.f;
#pragma unroll
    for (int ss = 0; ss < S_SAMP; ++ss) acc += cnred[rr][ss][a];
    out[a * TB + row0 + rr] = acc * (1.0f / (float)S_SAMP);
  }
}

extern "C" void kernel_launch(void* const* d_in, const int* in_sizes, int n_in,
                              void* d_out, int out_size, void* d_ws, size_t ws_size,
                              hipStream_t stream) {
  const float* q_vals = (const float*)d_in[0];
  const float* states = (const float*)d_in[1];
  const float* hw1_k1 = (const float*)d_in[2];
  const float* hw1_b1 = (const float*)d_in[3];
  const float* hw1_k2 = (const float*)d_in[4];
  const float* hw1_b2 = (const float*)d_in[5];
  const float* b1_k   = (const float*)d_in[6];
  const float* b1_b   = (const float*)d_in[7];
  const float* hw2_k1 = (const float*)d_in[8];
  const float* hw2_b1 = (const float*)d_in[9];
  const float* hw2_k2 = (const float*)d_in[10];
  const float* hw2_b2 = (const float*)d_in[11];
  const float* hb2_k1 = (const float*)d_in[12];
  const float* hb2_b1 = (const float*)d_in[13];
  const float* hb2_k2 = (const float*)d_in[14];
  const float* hb2_b2 = (const float*)d_in[15];
  float* out = (float*)d_out;

  const size_t need = (size_t)WT_ELEMS * sizeof(unsigned short);
  if (ws_size >= need) {
    unsigned short* wt = (unsigned short*)d_ws;
    wt_transpose<<<dim3(72), 256, 0, stream>>>(
        hw1_k1, hw2_k1, hw1_k2, b1_k, hb2_k1, hw2_k2, wt);
    alpha_mfma3<<<dim3(TB / RPB), 512, 0, stream>>>(
        q_vals, states, hw1_b1, hw1_b2, b1_b, hw2_b1, hw2_b2, hb2_b1,
        hb2_k2, hb2_b2, wt, out);
  } else {
    alpha_fused2<<<dim3(TB / FB_RPB), 256, 0, stream>>>(
        q_vals, states, hw1_k1, hw1_b1, hw1_k2, hw1_b2, b1_k, b1_b,
        hw2_k1, hw2_b1, hw2_k2, hw2_b2, hb2_k1, hb2_b1, hb2_k2, hb2_b2, out);
  }
}

// Round 16
// 33.633 us; speedup vs baseline: 1.4013x; 1.0106x over previous
//
#include <hip/hip_runtime.h>
#include <stdint.h>

// Problem constants (from reference)
#define N_AG   8
#define S_SAMP 16
#define TB     8192      // T*B
#define DST    128       // D_STATE
#define E_DIM  64

#define RPB    16        // rows per block -> 512 blocks, 512 threads (8 waves)
#define CN_STR 9         // cn stride: spreads 16 samples over banks

// WT layout in d_ws (bf16 element offsets): [n][k] row-major, k-stride 128
#define WT1K1  0         // hw1_k1^T  [128][128]
#define WT2K1  16384     // hw2_k1^T  [128][128]
#define WT1K2  32768     // hw1_k2^T  [128][128]
#define WTM3   49152     // rows 0..63 = b1_k^T, rows 64..127 = hb2_k1^T
#define WT2K2  65536     // hw2_k2^T  [64][128]
#define WT_ELEMS 73728   // total bf16 elements (147456 B)

typedef __attribute__((ext_vector_type(8))) short  short8v;   // 8 bf16 = 4 VGPR
typedef __attribute__((ext_vector_type(4))) float  float4v;   // C/D frag

__device__ __forceinline__ float4 ld4(const float* p) { return *(const float4*)p; }

// f32 -> bf16 round-to-nearest-even
__device__ __forceinline__ unsigned short f2bf(float f) {
  uint32_t x = __float_as_uint(f);
  return (unsigned short)((x + 0x7FFFu + ((x >> 16) & 1u)) >> 16);
}
__device__ __forceinline__ uint32_t pk2(float lo, float hi) {
  return (uint32_t)f2bf(lo) | ((uint32_t)f2bf(hi) << 16);
}

// ---------------- JAX threefry2x32 (20 rounds) ----------------
__device__ __forceinline__ uint2 tf2x32(uint32_t k0, uint32_t k1,
                                        uint32_t c0, uint32_t c1) {
  uint32_t ks2 = k0 ^ k1 ^ 0x1BD11BDAu;
  uint32_t x0 = c0 + k0, x1 = c1 + k1;
#define TFR(r) { x0 += x1; x1 = (x1 << (r)) | (x1 >> (32 - (r))); x1 ^= x0; }
  TFR(13) TFR(15) TFR(26) TFR(6)
  x0 += k1;  x1 += ks2 + 1u;
  TFR(17) TFR(29) TFR(16) TFR(24)
  x0 += ks2; x1 += k0 + 2u;
  TFR(13) TFR(15) TFR(26) TFR(6)
  x0 += k0;  x1 += k1 + 3u;
  TFR(17) TFR(29) TFR(16) TFR(24)
  x0 += k1;  x1 += ks2 + 4u;
  TFR(13) TFR(15) TFR(26) TFR(6)
  x0 += ks2; x1 += k0 + 5u;
#undef TFR
  return make_uint2(x0, x1);
}

// Swizzled bf16 LDS tile helpers (R9-verified): rows 256B, byte ^= (row&7)<<4
__device__ __forceinline__ short8v rdfrag(const unsigned short* base, int row, int ks, int lhi) {
  const int b = (row * 256 + ks * 64 + lhi * 16) ^ ((row & 7) << 4);
  return *(const short8v*)((const char*)base + b);
}
__device__ __forceinline__ void wrbf(unsigned short* pan, int r, int c, float v) {
  const int b = (r * 256 + c * 2) ^ ((r & 7) << 4);
  *(unsigned short*)((char*)pan + b) = f2bf(v);
}
// B-fragment directly from global pre-transposed bf16 (R10-verified)
__device__ __forceinline__ short8v gfrag(const unsigned short* wt, int n, int ks, int lhi) {
  return *(const short8v*)(wt + (n << 7) + ks * 32 + lhi * 8);
}

// ========== K0: transpose+convert all weights to bf16 [n][k] in d_ws (R10-verified) ==========
__global__ __launch_bounds__(256)
void wt_transpose(const float* __restrict__ hw1_k1, const float* __restrict__ hw2_k1,
                  const float* __restrict__ hw1_k2, const float* __restrict__ b1_k,
                  const float* __restrict__ hb2_k1, const float* __restrict__ hw2_k2,
                  unsigned short* __restrict__ wt)
{
  __shared__ float t[32][33];
  const int b = blockIdx.x;
  const float* src; int ldn, t0, dstbase;
  if (b < 16)      { src = hw1_k1; ldn = 128; t0 = b;      dstbase = WT1K1; }
  else if (b < 32) { src = hw2_k1; ldn = 128; t0 = b - 16; dstbase = WT2K1; }
  else if (b < 48) { src = hw1_k2; ldn = 128; t0 = b - 32; dstbase = WT1K2; }
  else if (b < 56) { src = b1_k;   ldn = 64;  t0 = b - 48; dstbase = WTM3; }
  else if (b < 64) { src = hb2_k1; ldn = 64;  t0 = b - 56; dstbase = WTM3 + 64 * 128; }
  else             { src = hw2_k2; ldn = 64;  t0 = b - 64; dstbase = WT2K2; }
  const int kt = t0 & 3, nt = t0 >> 2;
  const int tid = threadIdx.x;
  {
    const int c = tid & 31;
    for (int r = tid >> 5; r < 32; r += 8)
      t[r][c] = src[(size_t)(kt * 32 + r) * ldn + nt * 32 + c];
  }
  __syncthreads();
  {
    const int c2 = tid & 15;
    for (int n = tid >> 4; n < 32; n += 16) {
      const uint32_t v = pk2(t[2 * c2][n], t[2 * c2 + 1][n]);
      *(uint32_t*)&wt[dstbase + (nt * 32 + n) * 128 + kt * 32 + 2 * c2] = v;
    }
  }
}

// ========================= Main fused kernel =========================
// R15-verified structure (RPB=16, 512 threads, full M=16 tiles, balanced RNG).
// R16 change: M5 moved to waves 4-7 so post-barrier work is balanced
// (waves 0-3: M4 + b2-dot; waves 4-7: M4 + M5). Single-writer per w2l slot.
__global__ __launch_bounds__(512, 4)
void alpha_mfma3(const float* __restrict__ q_vals,   // (8, 8192)
                 const float* __restrict__ states,   // (8192, 128)
                 const float* __restrict__ hw1_b1, const float* __restrict__ hw1_b2,
                 const float* __restrict__ b1_b,   const float* __restrict__ hw2_b1,
                 const float* __restrict__ hw2_b2, const float* __restrict__ hb2_b1,
                 const float* __restrict__ hb2_k2, const float* __restrict__ hb2_b2,
                 const unsigned short* __restrict__ wt,
                 float* __restrict__ out)            // (8, 8192)
{
  __shared__ unsigned short xbf[RPB * 128];     // X bf16 swz            4 KB
  __shared__ unsigned short h1bf[RPB * 128];    // relu(h1) bf16 swz     4 KB
  __shared__ unsigned short h2bf[RPB * 128];    // relu(h2) bf16 swz     4 KB
  __shared__ float w1l[RPB][132];               // |w1| f32            8.4 KB
  __shared__ float b1l[RPB][68];                //                     4.3 KB
  __shared__ float w2l[RPB][68];                //                     4.3 KB
  __shared__ float hbl[RPB][68];                //                     4.3 KB
  __shared__ float b2l[RPB];
  __shared__ float ql[RPB][N_AG];
  __shared__ float cn_l[RPB][S_SAMP][CN_STR];   // cn then |y|         9.2 KB

  const int tid  = threadIdx.x;
  const int row0 = blockIdx.x * RPB;
  const int lane = tid & 63;
  const int wv   = tid >> 6;        // wave 0..7
  const int lrow = lane & 15;       // A-row / B-col within a 16-tile
  const int lhi  = lane >> 4;       // k-group; C rows lhi*4+j (ALL 16 used)

  // ---- P0: X f32 -> bf16 swz LDS (16 rows, 512 float4 = 1/thread); q load ----
  {
    const int r = tid >> 5, k0 = (tid & 31) * 4;
    const float4 v = ld4(&states[(size_t)(row0 + r) * DST + k0]);
    const int b = (r * 256 + k0 * 2) ^ ((r & 7) << 4);
    *(uint32_t*)((char*)xbf + b)     = pk2(v.x, v.y);
    *(uint32_t*)((char*)xbf + b + 4) = pk2(v.z, v.w);
  }
  if (tid < RPB * N_AG) {
    const int rr = tid >> 3, a = tid & 7;
    ql[rr][a] = q_vals[a * TB + row0 + rr];
  }
  __syncthreads();

  // ---- RNG: one (row, sample) per thread, tid<256 = waves 0-3 (verified chain) ----
  if (tid < RPB * S_SAMP) {
    const int r  = tid >> 4;
    const int sl = tid & 15;
    const uint32_t j = (uint32_t)(row0 + r) * (uint32_t)S_SAMP + (uint32_t)sl;
    uint2 kj  = tf2x32(0u, 42u, 0u, j);       // partitionable split of key(42)
    uint2 sub = tf2x32(kj.x, kj.y, 0u, 1u);   // subkey = split(key_j)[1]
    uint32_t K[N_AG];
#pragma unroll
    for (int i = 0; i < N_AG; ++i) {
      uint2 b = tf2x32(sub.x, sub.y, 0u, (uint32_t)i);
      K[i] = b.x ^ b.y;
    }
    int posa[N_AG];
#pragma unroll
    for (int i = 0; i < N_AG; ++i) {
      int rank = 0;
#pragma unroll
      for (int m = 0; m < N_AG; ++m)
        rank += (K[m] < K[i]) || (K[m] == K[i] && m < i);
      posa[rank] = i;
    }
#pragma unroll
    for (int a = 0; a < N_AG; ++a) {
      const int pa = posa[a];
      float cs = 0.f;
#pragma unroll
      for (int a2 = 0; a2 < N_AG; ++a2)
        cs += (posa[a2] < pa) ? ql[r][a2] : 0.f;
      cn_l[r][sl][a] = cs / (float)max(pa, 1);
    }
  }

  // ===== M1: h1 = relu(X @ hw1_k1 + b) -> h1bf  (8 waves x 16 cols) =====
  {
    float4v a0 = {0.f,0.f,0.f,0.f};
    const int c = wv * 16 + lrow;
#pragma unroll
    for (int ks = 0; ks < 4; ++ks) {
      const short8v af = rdfrag(xbf, lrow, ks, lhi);
      a0 = __builtin_amdgcn_mfma_f32_16x16x32_bf16(af, gfrag(wt + WT1K1, c, ks, lhi), a0, 0, 0, 0);
    }
    const float bv = hw1_b1[c];
#pragma unroll
    for (int j = 0; j < 4; ++j)
      wrbf(h1bf, lhi * 4 + j, c, fmaxf(a0[j] + bv, 0.f));
  }

  // ===== M2: h2 = relu(X @ hw2_k1 + b) -> h2bf =====
  {
    float4v a0 = {0.f,0.f,0.f,0.f};
    const int c = wv * 16 + lrow;
#pragma unroll
    for (int ks = 0; ks < 4; ++ks) {
      const short8v af = rdfrag(xbf, lrow, ks, lhi);
      a0 = __builtin_amdgcn_mfma_f32_16x16x32_bf16(af, gfrag(wt + WT2K1, c, ks, lhi), a0, 0, 0, 0);
    }
    const float bv = hw2_b1[c];
#pragma unroll
    for (int j = 0; j < 4; ++j)
      wrbf(h2bf, lhi * 4 + j, c, fmaxf(a0[j] + bv, 0.f));
  }

  // ===== M3: cols 0..63 -> b1 = X@b1_k + b; 64..127 -> hb = relu(X@hb2_k1 + b) =====
  {
    float4v a0 = {0.f,0.f,0.f,0.f};
    const int c = wv * 16 + lrow;
#pragma unroll
    for (int ks = 0; ks < 4; ++ks) {
      const short8v af = rdfrag(xbf, lrow, ks, lhi);
      a0 = __builtin_amdgcn_mfma_f32_16x16x32_bf16(af, gfrag(wt + WTM3, c, ks, lhi), a0, 0, 0, 0);
    }
    if (c < 64) {
      const float bv = b1_b[c];
#pragma unroll
      for (int j = 0; j < 4; ++j)
        b1l[lhi * 4 + j][c] = a0[j] + bv;
    } else {
      const float bv = hb2_b1[c - 64];
#pragma unroll
      for (int j = 0; j < 4; ++j)
        hbl[lhi * 4 + j][c - 64] = fmaxf(a0[j] + bv, 0.f);
    }
  }
  __syncthreads();   // h1bf/h2bf/b1l/hbl/cn_l now visible

  // ---- b2[r] (waves 0-3) ----
  if (tid < RPB * S_SAMP) {
    const int r = tid >> 4, sl = tid & 15;
    float v = hbl[r][sl]      * hb2_k2[sl]
            + hbl[r][sl + 16] * hb2_k2[sl + 16]
            + hbl[r][sl + 32] * hb2_k2[sl + 32]
            + hbl[r][sl + 48] * hb2_k2[sl + 48];
    v += __shfl_down(v, 8, 16); v += __shfl_down(v, 4, 16);
    v += __shfl_down(v, 2, 16); v += __shfl_down(v, 1, 16);
    if (sl == 0) b2l[r] = v + hb2_b2[0];
  }

  // ===== M5: w2 = |h2 @ hw2_k2 + b| (waves 4-7; balanced vs b2 on 0-3) =====
  if (wv >= 4) {
    float4v a0 = {0.f,0.f,0.f,0.f};
    const int c = (wv - 4) * 16 + lrow;
#pragma unroll
    for (int ks = 0; ks < 4; ++ks) {
      const short8v af = rdfrag(h2bf, lrow, ks, lhi);
      a0 = __builtin_amdgcn_mfma_f32_16x16x32_bf16(af, gfrag(wt + WT2K2, c, ks, lhi), a0, 0, 0, 0);
    }
    const float bv = hw2_b2[c];
#pragma unroll
    for (int j = 0; j < 4; ++j)
      w2l[lhi * 4 + j][c] = fabsf(a0[j] + bv);
  }

  // ===== M4: w1 = |h1 @ hw1_k2 + b| -> w1l (f32), all waves =====
  {
    float4v a0 = {0.f,0.f,0.f,0.f};
    const int c = wv * 16 + lrow;
#pragma unroll
    for (int ks = 0; ks < 4; ++ks) {
      const short8v af = rdfrag(h1bf, lrow, ks, lhi);
      a0 = __builtin_amdgcn_mfma_f32_16x16x32_bf16(af, gfrag(wt + WT1K2, c, ks, lhi), a0, 0, 0, 0);
    }
    const float bv = hw1_b2[c];
#pragma unroll
    for (int j = 0; j < 4; ++j)
      w1l[lhi * 4 + j][c] = fabsf(a0[j] + bv);
  }
  __syncthreads();   // w1l/w2l/b2l visible

  // ===== Main: thread = (r in 16, sl in 16, agent-half in 2); all 512 active =====
  {
    const int sl  = tid & 15;
    const int r   = (tid >> 4) & 15;
    const int a0i = (tid >> 8) * 4;   // agents a0i..a0i+3
    float cn[4], qv[4], y[4];
#pragma unroll
    for (int jj = 0; jj < 4; ++jj) {
      cn[jj] = cn_l[r][sl][a0i + jj];
      qv[jj] = ql[r][a0i + jj];
      y[jj]  = 0.f;
    }
#pragma unroll 4
    for (int e = 0; e < E_DIM; e += 4) {
      const float4 wa  = ld4(&w1l[r][e]);
      const float4 wb  = ld4(&w1l[r][64 + e]);
      const float4 bb  = ld4(&b1l[r][e]);
      const float4 w2v = ld4(&w2l[r][e]);
#pragma unroll
      for (int jj = 0; jj < 4; ++jj) {
        float h;
        h = fmaf(cn[jj], wa.x, fmaf(qv[jj], wb.x, bb.x));
        y[jj] = fmaf((h > 0.f) ? h : (__expf(h) - 1.f), w2v.x, y[jj]);
        h = fmaf(cn[jj], wa.y, fmaf(qv[jj], wb.y, bb.y));
        y[jj] = fmaf((h > 0.f) ? h : (__expf(h) - 1.f), w2v.y, y[jj]);
        h = fmaf(cn[jj], wa.z, fmaf(qv[jj], wb.z, bb.z));
        y[jj] = fmaf((h > 0.f) ? h : (__expf(h) - 1.f), w2v.z, y[jj]);
        h = fmaf(cn[jj], wa.w, fmaf(qv[jj], wb.w, bb.w));
        y[jj] = fmaf((h > 0.f) ? h : (__expf(h) - 1.f), w2v.w, y[jj]);
      }
    }
    const float b2v = b2l[r];
#pragma unroll
    for (int jj = 0; jj < 4; ++jj)
      cn_l[r][sl][a0i + jj] = fabsf(y[jj] + b2v);   // own slots only
  }
  __syncthreads();

  // ---- Reduce over samples; rr = tid&15 so 16 consecutive rows coalesce ----
  if (tid < RPB * N_AG) {
    const int rr = tid & 15, a = tid >> 4;
    float acc = 0.f;
#pragma unroll
    for (int ss = 0; ss < S_SAMP; ++ss) acc += cn_l[rr][ss][a];
    out[a * TB + row0 + rr] = acc * (1.0f / (float)S_SAMP);
  }
}

// ============ Fallback (R4-structure, proven): used only if ws too small ============
#define FB_RPB 16
#define FB_H_PAD 132
#define FB_E_PAD 68
__global__ __launch_bounds__(256)
void alpha_fused2(const float* __restrict__ q_vals, const float* __restrict__ states,
                  const float* __restrict__ hw1_k1, const float* __restrict__ hw1_b1,
                  const float* __restrict__ hw1_k2, const float* __restrict__ hw1_b2,
                  const float* __restrict__ b1_k,   const float* __restrict__ b1_b,
                  const float* __restrict__ hw2_k1, const float* __restrict__ hw2_b1,
                  const float* __restrict__ hw2_k2, const float* __restrict__ hw2_b2,
                  const float* __restrict__ hb2_k1, const float* __restrict__ hb2_b1,
                  const float* __restrict__ hb2_k2, const float* __restrict__ hb2_b2,
                  float* __restrict__ out)
{
  __shared__ float s_lds[FB_RPB][DST];
  __shared__ float scratch[FB_RPB][FB_H_PAD];
  __shared__ float scratch2[FB_RPB][FB_E_PAD];
  __shared__ float w1l[FB_RPB][FB_H_PAD];
  __shared__ float b1l[FB_RPB][FB_E_PAD];
  __shared__ float w2l[FB_RPB][FB_E_PAD];
  __shared__ float b2l[FB_RPB];
  __shared__ float qlf[FB_RPB][N_AG];
  __shared__ float cnred[FB_RPB][S_SAMP][N_AG];
  const int tid = threadIdx.x;
  const int row0 = blockIdx.x * FB_RPB;
  const int r = tid >> 4, sl = tid & 15;
  {
    const float4* src = reinterpret_cast<const float4*>(states + (size_t)row0 * DST);
    reinterpret_cast<float4*>(&s_lds[0][0])[tid]       = src[tid];
    reinterpret_cast<float4*>(&s_lds[0][0])[tid + 256] = src[tid + 256];
  }
  if (tid < FB_RPB * N_AG) {
    const int rr = tid >> 3, a = tid & 7;
    qlf[rr][a] = q_vals[a * TB + row0 + rr];
  }
  __syncthreads();
  {
    const uint32_t j = (uint32_t)(row0 + r) * (uint32_t)S_SAMP + (uint32_t)sl;
    uint2 kj = tf2x32(0u, 42u, 0u, j);
    uint2 sub = tf2x32(kj.x, kj.y, 0u, 1u);
    uint32_t K[N_AG];
#pragma unroll
    for (int i = 0; i < N_AG; ++i) { uint2 b = tf2x32(sub.x, sub.y, 0u, (uint32_t)i); K[i] = b.x ^ b.y; }
    int posa[N_AG];
#pragma unroll
    for (int i = 0; i < N_AG; ++i) {
      int rank = 0;
#pragma unroll
      for (int m = 0; m < N_AG; ++m) rank += (K[m] < K[i]) || (K[m] == K[i] && m < i);
      posa[rank] = i;
    }
#pragma unroll
    for (int a = 0; a < N_AG; ++a) {
      const int pa = posa[a];
      float cs = 0.f;
#pragma unroll
      for (int a2 = 0; a2 < N_AG; ++a2) cs += (posa[a2] < pa) ? qlf[r][a2] : 0.f;
      cnred[r][sl][a] = cs / (float)max(pa, 1);
    }
  }
  {
    int c = tid & 127, rg = tid >> 7;
    float a0=0.f,a1=0.f,a2=0.f,a3=0.f,a4=0.f,a5=0.f,a6=0.f,a7=0.f;
#pragma unroll 2
    for (int k = 0; k < DST; ++k) {
      float wv = hw1_k1[k * 128 + c];
      a0 += s_lds[rg*8+0][k]*wv; a1 += s_lds[rg*8+1][k]*wv;
      a2 += s_lds[rg*8+2][k]*wv; a3 += s_lds[rg*8+3][k]*wv;
      a4 += s_lds[rg*8+4][k]*wv; a5 += s_lds[rg*8+5][k]*wv;
      a6 += s_lds[rg*8+6][k]*wv; a7 += s_lds[rg*8+7][k]*wv;
    }
    float b = hw1_b1[c];
    scratch[rg*8+0][c]=fmaxf(a0+b,0.f); scratch[rg*8+1][c]=fmaxf(a1+b,0.f);
    scratch[rg*8+2][c]=fmaxf(a2+b,0.f); scratch[rg*8+3][c]=fmaxf(a3+b,0.f);
    scratch[rg*8+4][c]=fmaxf(a4+b,0.f); scratch[rg*8+5][c]=fmaxf(a5+b,0.f);
    scratch[rg*8+6][c]=fmaxf(a6+b,0.f); scratch[rg*8+7][c]=fmaxf(a7+b,0.f);
  }
  {
    int c = tid & 63, rg = tid >> 6;
    float a0=0.f,a1=0.f,a2=0.f,a3=0.f;
#pragma unroll 2
    for (int k = 0; k < DST; ++k) {
      float wv = b1_k[k * 64 + c];
      a0 += s_lds[rg*4+0][k]*wv; a1 += s_lds[rg*4+1][k]*wv;
      a2 += s_lds[rg*4+2][k]*wv; a3 += s_lds[rg*4+3][k]*wv;
    }
    float b = b1_b[c];
    b1l[rg*4+0][c]=a0+b; b1l[rg*4+1][c]=a1+b; b1l[rg*4+2][c]=a2+b; b1l[rg*4+3][c]=a3+b;
  }
  __syncthreads();
  {
    int c = tid & 127, rg = tid >> 7;
    float a0=0.f,a1=0.f,a2=0.f,a3=0.f,a4=0.f,a5=0.f,a6=0.f,a7=0.f;
#pragma unroll 2
    for (int k = 0; k < DST; ++k) {
      float wv = hw1_k2[k * 128 + c];
      a0 += scratch[rg*8+0][k]*wv; a1 += scratch[rg*8+1][k]*wv;
      a2 += scratch[rg*8+2][k]*wv; a3 += scratch[rg*8+3][k]*wv;
      a4 += scratch[rg*8+4][k]*wv; a5 += scratch[rg*8+5][k]*wv;
      a6 += scratch[rg*8+6][k]*wv; a7 += scratch[rg*8+7][k]*wv;
    }
    float b = hw1_b2[c];
    w1l[rg*8+0][c]=fabsf(a0+b); w1l[rg*8+1][c]=fabsf(a1+b);
    w1l[rg*8+2][c]=fabsf(a2+b); w1l[rg*8+3][c]=fabsf(a3+b);
    w1l[rg*8+4][c]=fabsf(a4+b); w1l[rg*8+5][c]=fabsf(a5+b);
    w1l[rg*8+6][c]=fabsf(a6+b); w1l[rg*8+7][c]=fabsf(a7+b);
  }
  {
    int c = tid & 63, rg = tid >> 6;
    float a0=0.f,a1=0.f,a2=0.f,a3=0.f;
#pragma unroll 2
    for (int k = 0; k < DST; ++k) {
      float wv = hb2_k1[k * 64 + c];
      a0 += s_lds[rg*4+0][k]*wv; a1 += s_lds[rg*4+1][k]*wv;
      a2 += s_lds[rg*4+2][k]*wv; a3 += s_lds[rg*4+3][k]*wv;
    }
    float b = hb2_b1[c];
    scratch2[rg*4+0][c]=fmaxf(a0+b,0.f); scratch2[rg*4+1][c]=fmaxf(a1+b,0.f);
    scratch2[rg*4+2][c]=fmaxf(a2+b,0.f); scratch2[rg*4+3][c]=fmaxf(a3+b,0.f);
  }
  __syncthreads();
  {
    int c = tid & 127, rg = tid >> 7;
    float a0=0.f,a1=0.f,a2=0.f,a3=0.f,a4=0.f,a5=0.f,a6=0.f,a7=0.f;
#pragma unroll 2
    for (int k = 0; k < DST; ++k) {
      float wv = hw2_k1[k * 128 + c];
      a0 += s_lds[rg*8+0][k]*wv; a1 += s_lds[rg*8+1][k]*wv;
      a2 += s_lds[rg*8+2][k]*wv; a3 += s_lds[rg*8+3][k]*wv;
      a4 += s_lds[rg*8+4][k]*wv; a5 += s_lds[rg*8+5][k]*wv;
      a6 += s_lds[rg*8+6][k]*wv; a7 += s_lds[rg*8+7][k]*wv;
    }
    float b = hw2_b1[c];
    scratch[rg*8+0][c]=fmaxf(a0+b,0.f); scratch[rg*8+1][c]=fmaxf(a1+b,0.f);
    scratch[rg*8+2][c]=fmaxf(a2+b,0.f); scratch[rg*8+3][c]=fmaxf(a3+b,0.f);
    scratch[rg*8+4][c]=fmaxf(a4+b,0.f); scratch[rg*8+5][c]=fmaxf(a5+b,0.f);
    scratch[rg*8+6][c]=fmaxf(a6+b,0.f); scratch[rg*8+7][c]=fmaxf(a7+b,0.f);
  }
  if (tid < FB_RPB * S_SAMP) {
    float v = scratch2[r][sl]      * hb2_k2[sl]
            + scratch2[r][sl + 16] * hb2_k2[sl + 16]
            + scratch2[r][sl + 32] * hb2_k2[sl + 32]
            + scratch2[r][sl + 48] * hb2_k2[sl + 48];
    v += __shfl_down(v, 8, 16); v += __shfl_down(v, 4, 16);
    v += __shfl_down(v, 2, 16); v += __shfl_down(v, 1, 16);
    if (sl == 0) b2l[r] = v + hb2_b2[0];
  }
  __syncthreads();
  {
    int c = tid & 63, rg = tid >> 6;
    float a0=0.f,a1=0.f,a2=0.f,a3=0.f;
#pragma unroll 2
    for (int k = 0; k < DST; ++k) {
      float wv = hw2_k2[k * 64 + c];
      a0 += scratch[rg*4+0][k]*wv; a1 += scratch[rg*4+1][k]*wv;
      a2 += scratch[rg*4+2][k]*wv; a3 += scratch[rg*4+3][k]*wv;
    }
    float b = hw2_b2[c];
    w2l[rg*4+0][c]=fabsf(a0+b); w2l[rg*4+1][c]=fabsf(a1+b);
    w2l[rg*4+2][c]=fabsf(a2+b); w2l[rg*4+3][c]=fabsf(a3+b);
  }
  __syncthreads();
  {
    float cn[N_AG], qv[N_AG], y[N_AG];
#pragma unroll
    for (int a = 0; a < N_AG; ++a) { cn[a]=cnred[r][sl][a]; qv[a]=qlf[r][a]; y[a]=0.f; }
#pragma unroll 4
    for (int e = 0; e < E_DIM; e += 4) {
      const float4 wa  = ld4(&w1l[r][e]);
      const float4 wb  = ld4(&w1l[r][64 + e]);
      const float4 bb  = ld4(&b1l[r][e]);
      const float4 w2v = ld4(&w2l[r][e]);
#pragma unroll
      for (int a = 0; a < N_AG; ++a) {
        float h;
        h = fmaf(cn[a], wa.x, fmaf(qv[a], wb.x, bb.x));
        y[a] = fmaf((h > 0.f) ? h : (__expf(h) - 1.f), w2v.x, y[a]);
        h = fmaf(cn[a], wa.y, fmaf(qv[a], wb.y, bb.y));
        y[a] = fmaf((h > 0.f) ? h : (__expf(h) - 1.f), w2v.y, y[a]);
        h = fmaf(cn[a], wa.z, fmaf(qv[a], wb.z, bb.z));
        y[a] = fmaf((h > 0.f) ? h : (__expf(h) - 1.f), w2v.z, y[a]);
        h = fmaf(cn[a], wa.w, fmaf(qv[a], wb.w, bb.w));
        y[a] = fmaf((h > 0.f) ? h : (__expf(h) - 1.f), w2v.w, y[a]);
      }
    }
    const float b2v = b2l[r];
#pragma unroll
    for (int a = 0; a < N_AG; ++a) cnred[r][sl][a] = fabsf(y[a] + b2v);
  }
  __syncthreads();
  if (tid < FB_RPB * N_AG) {
    const int a = tid >> 4, rr = tid & 15;
    float acc = 0.f;
#pragma unroll
    for (int ss = 0; ss < S_SAMP; ++ss) acc += cnred[rr][ss][a];
    out[a * TB + row0 + rr] = acc * (1.0f / (float)S_SAMP);
  }
}

extern "C" void kernel_launch(void* const* d_in, const int* in_sizes, int n_in,
                              void* d_out, int out_size, void* d_ws, size_t ws_size,
                              hipStream_t stream) {
  const float* q_vals = (const float*)d_in[0];
  const float* states = (const float*)d_in[1];
  const float* hw1_k1 = (const float*)d_in[2];
  const float* hw1_b1 = (const float*)d_in[3];
  const float* hw1_k2 = (const float*)d_in[4];
  const float* hw1_b2 = (const float*)d_in[5];
  const float* b1_k   = (const float*)d_in[6];
  const float* b1_b   = (const float*)d_in[7];
  const float* hw2_k1 = (const float*)d_in[8];
  const float* hw2_b1 = (const float*)d_in[9];
  const float* hw2_k2 = (const float*)d_in[10];
  const float* hw2_b2 = (const float*)d_in[11];
  const float* hb2_k1 = (const float*)d_in[12];
  const float* hb2_b1 = (const float*)d_in[13];
  const float* hb2_k2 = (const float*)d_in[14];
  const float* hb2_b2 = (const float*)d_in[15];
  float* out = (float*)d_out;

  const size_t need = (size_t)WT_ELEMS * sizeof(unsigned short);
  if (ws_size >= need) {
    unsigned short* wt = (unsigned short*)d_ws;
    wt_transpose<<<dim3(72), 256, 0, stream>>>(
        hw1_k1, hw2_k1, hw1_k2, b1_k, hb2_k1, hw2_k2, wt);
    alpha_mfma3<<<dim3(TB / RPB), 512, 0, stream>>>(
        q_vals, states, hw1_b1, hw1_b2, b1_b, hw2_b1, hw2_b2, hb2_b1,
        hb2_k2, hb2_b2, wt, out);
  } else {
    alpha_fused2<<<dim3(TB / FB_RPB), 256, 0, stream>>>(
        q_vals, states, hw1_k1, hw1_b1, hw1_k2, hw1_b2, b1_k, b1_b,
        hw2_k1, hw2_b1, hw2_k2, hw2_b2, hb2_k1, hb2_b1, hb2_k2, hb2_b2, out);
  }
}